// Round 1
// baseline (355.475 us; speedup 1.0000x reference)
//
#include <hip/hip_runtime.h>
#include <hip/hip_bf16.h>

typedef __bf16 bf16_t;
typedef bf16_t bf16x8 __attribute__((ext_vector_type(8)));
typedef float f32x4 __attribute__((ext_vector_type(4)));

// ---------------- constants ----------------
// input: [32, 2, 256, 256] fp32 binary
// w1: [30, 2, 5, 5] fp32 ; w2: [100, 30, 5, 5] fp32
// pooled (post conv1+fire+pool, padded by 1): logical [32][131][131] x 30ch
// stored as bf16 [t][131][132][32]  (x padded to 132, ch padded to 32)
#define PB_H 131
#define PB_W 132
#define CI   32
#define POOL_ELEMS ((size_t)32 * PB_H * PB_W * CI)          // 17,707,008
#define W2R_BYTES  (5 * 5 * 112 * 32 * 2)                    // 179,200
#define N_POOL_PIX (32 * 129 * 129)                          // 532,898

// ---------------- kernel 1: repack w2 -> bf16 [ky][kx][112][32] ----------------
__global__ void repack_w2_kernel(const float* __restrict__ w2, bf16_t* __restrict__ w2r) {
    int idx = blockIdx.x * 256 + threadIdx.x;                // 0 .. 89599
    if (idx >= 5 * 5 * 112 * 32) return;
    int i  = idx & 31;
    int m  = (idx >> 5) % 112;
    int kk = idx / (112 * 32);
    int ky = kk / 5, kx = kk % 5;
    float v = 0.0f;
    if (m < 100 && i < 30) v = w2[((m * 30 + i) * 5 + ky) * 5 + kx];
    w2r[idx] = (bf16_t)v;
}

// ---------------- kernel 2: conv1 + fire(15) + maxpool(2,2,pad1) ----------------
__device__ __forceinline__ unsigned conv1_mask30(const float* __restrict__ w1, const float x[50]) {
    unsigned mask = 0;
    for (int c = 0; c < 30; ++c) {
        const float* wc = w1 + c * 50;
        float p0 = 0.f, p1 = 0.f, p2 = 0.f, p3 = 0.f;
        #pragma unroll
        for (int k = 0; k < 48; k += 4) {
            p0 = fmaf(wc[k + 0], x[k + 0], p0);
            p1 = fmaf(wc[k + 1], x[k + 1], p1);
            p2 = fmaf(wc[k + 2], x[k + 2], p2);
            p3 = fmaf(wc[k + 3], x[k + 3], p3);
        }
        p0 = fmaf(wc[48], x[48], p0);
        p1 = fmaf(wc[49], x[49], p1);
        float pot = (p0 + p1) + (p2 + p3);
        if (pot > 15.0f) mask |= (1u << c);
    }
    return mask;
}

__global__ __launch_bounds__(256) void conv1_pool_kernel(const float* __restrict__ in,
                                                         const float* __restrict__ w1,
                                                         bf16_t* __restrict__ pool) {
    int idx = blockIdx.x * 256 + threadIdx.x;
    if (idx >= N_POOL_PIX) return;
    int t   = idx / (129 * 129);
    int rem = idx % (129 * 129);
    int py  = rem / 129, px = rem % 129;

    const float* inT = in + (size_t)t * 2 * 256 * 256;
    unsigned mask = 0;

    #pragma unroll
    for (int dy = 0; dy < 2; ++dy) {
        int sy = 2 * py - 1 + dy;
        if ((unsigned)sy > 255u) continue;                   // -inf pool pad
        #pragma unroll
        for (int dx = 0; dx < 2; ++dx) {
            int sx = 2 * px - 1 + dx;
            if ((unsigned)sx > 255u) continue;
            int y0 = sy - 2, x0 = sx - 2;                    // conv input pad = 2
            float x[50];
            if (y0 >= 0 && y0 <= 251 && x0 >= 0 && x0 <= 251) {
                #pragma unroll
                for (int i = 0; i < 2; ++i)
                    #pragma unroll
                    for (int ky = 0; ky < 5; ++ky)
                        #pragma unroll
                        for (int kx = 0; kx < 5; ++kx)
                            x[i * 25 + ky * 5 + kx] = inT[((size_t)i * 256 + (y0 + ky)) * 256 + (x0 + kx)];
            } else {
                #pragma unroll
                for (int i = 0; i < 2; ++i)
                    #pragma unroll
                    for (int ky = 0; ky < 5; ++ky)
                        #pragma unroll
                        for (int kx = 0; kx < 5; ++kx) {
                            int iy = y0 + ky, ix = x0 + kx;
                            bool ok = ((unsigned)iy < 256u) && ((unsigned)ix < 256u);
                            int cy = iy < 0 ? 0 : (iy > 255 ? 255 : iy);
                            int cx = ix < 0 ? 0 : (ix > 255 ? 255 : ix);
                            float v = inT[((size_t)i * 256 + cy) * 256 + cx];
                            x[i * 25 + ky * 5 + kx] = ok ? v : 0.0f;
                        }
            }
            mask |= conv1_mask30(w1, x);
        }
    }

    // write 32 bf16 (30 real + 2 zero pad) = 64 B, interior of padded buffer
    unsigned words[16];
    #pragma unroll
    for (int i2 = 0; i2 < 16; ++i2) {
        unsigned lo = ((mask >> (2 * i2)) & 1u) ? 0x3F80u : 0u;
        unsigned hi = ((mask >> (2 * i2 + 1)) & 1u) ? 0x3F80u : 0u;
        words[i2] = lo | (hi << 16);
    }
    size_t base = (((size_t)t * PB_H + (py + 1)) * PB_W + (px + 1)) * CI;
    uint4* dst = (uint4*)(pool + base);
    dst[0] = make_uint4(words[0],  words[1],  words[2],  words[3]);
    dst[1] = make_uint4(words[4],  words[5],  words[6],  words[7]);
    dst[2] = make_uint4(words[8],  words[9],  words[10], words[11]);
    dst[3] = make_uint4(words[12], words[13], words[14], words[15]);
}

// ---------------- kernel 3: conv2 (implicit GEMM, bf16 MFMA) + fire(10) + any ----------------
// block = (t, oy): M=112 (7 mtiles), N=128 pixels (8 ntiles, 2 per wave), K = 5ky*5kx steps of 32
__global__ __launch_bounds__(256, 2) void conv2_any_kernel(const bf16_t* __restrict__ pool,
                                                           const bf16_t* __restrict__ w2r,
                                                           float* __restrict__ out) {
    __shared__ __align__(16) bf16_t Bt[5 * PB_W * CI];   // 21,120 elems = 42,240 B
    __shared__ __align__(16) bf16_t At[5 * 112 * 32];    // 17,920 elems = 35,840 B

    int bx = blockIdx.x;
    int t = bx / 127, oy = bx % 127;
    int tid = threadIdx.x;

    // stage B tile: rows oy..oy+4, contiguous 21,120 bf16 in source
    const bf16_t* bsrc = pool + ((size_t)t * PB_H + oy) * PB_W * CI;
    for (int off = tid * 8; off < 5 * PB_W * CI; off += 256 * 8)
        *(uint4*)(Bt + off) = *(const uint4*)(bsrc + off);

    int lane = tid & 63, wv = tid >> 6;
    int quad = lane >> 4, l15 = lane & 15;
    int n0 = wv * 32 + l15;                               // pixel of ntile 2*wv

    f32x4 acc[7][2] = {};

    for (int ky = 0; ky < 5; ++ky) {
        __syncthreads();                                   // Bt ready / At consumers done
        const bf16_t* asrc = w2r + (size_t)ky * (5 * 112 * 32);
        for (int off = tid * 8; off < 5 * 112 * 32; off += 256 * 8)
            *(uint4*)(At + off) = *(const uint4*)(asrc + off);
        __syncthreads();

        #pragma unroll
        for (int kx = 0; kx < 5; ++kx) {
            bf16x8 a[7], b[2];
            #pragma unroll
            for (int mt = 0; mt < 7; ++mt)
                a[mt] = *(const bf16x8*)(At + ((kx * 112 + mt * 16 + l15) * 32 + quad * 8));
            #pragma unroll
            for (int j = 0; j < 2; ++j) {
                int x = n0 + j * 16 + kx;                  // buffer x = ox + kx
                b[j] = *(const bf16x8*)(Bt + ((ky * PB_W + x) * CI + quad * 8));
            }
            #pragma unroll
            for (int mt = 0; mt < 7; ++mt)
                #pragma unroll
                for (int j = 0; j < 2; ++j)
                    acc[mt][j] = __builtin_amdgcn_mfma_f32_16x16x32_bf16(a[mt], b[j], acc[mt][j], 0, 0, 0);
        }
    }

    // fire(10) + global any: C/D layout col(n)=lane&15, row(m)=quad*4+r
    int ox0 = n0, ox1 = n0 + 16;
    #pragma unroll
    for (int mt = 0; mt < 7; ++mt) {
        #pragma unroll
        for (int r = 0; r < 4; ++r) {
            int c = mt * 16 + quad * 4 + r;
            bool f0 = (acc[mt][0][r] > 10.0f) && (ox0 < 127);
            bool f1 = (acc[mt][1][r] > 10.0f) && (ox1 < 127);
            if (c < 100 && (f0 || f1)) out[c] = 1.0f;      // benign race: all write 1.0f
        }
    }
}

// ---------------- launch ----------------
extern "C" void kernel_launch(void* const* d_in, const int* in_sizes, int n_in,
                              void* d_out, int out_size, void* d_ws, size_t ws_size,
                              hipStream_t stream) {
    const float* in = (const float*)d_in[0];
    const float* w1 = (const float*)d_in[1];
    const float* w2 = (const float*)d_in[2];
    float* out = (float*)d_out;

    bf16_t* w2r  = (bf16_t*)d_ws;
    bf16_t* pool = (bf16_t*)((char*)d_ws + W2R_BYTES);

    hipMemsetAsync(out, 0, 100 * sizeof(float), stream);
    hipMemsetAsync(pool, 0, POOL_ELEMS * sizeof(bf16_t), stream);

    repack_w2_kernel<<<(5 * 5 * 112 * 32 + 255) / 256, 256, 0, stream>>>(w2, w2r);
    conv1_pool_kernel<<<(N_POOL_PIX + 255) / 256, 256, 0, stream>>>(in, w1, pool);
    conv2_any_kernel<<<32 * 127, 256, 0, stream>>>(pool, w2r, out);
}

// Round 3
// 265.586 us; speedup vs baseline: 1.3385x; 1.3385x over previous
//
#include <hip/hip_runtime.h>
#include <hip/hip_bf16.h>

typedef __bf16 bf16_t;
typedef bf16_t bf16x8 __attribute__((ext_vector_type(8)));
typedef float f32x4 __attribute__((ext_vector_type(4)));
typedef __fp16 h2 __attribute__((ext_vector_type(2)));   // matches cvt_pkrtz / fdot2

// ---------------- constants ----------------
// input: [32, 2, 256, 256] fp32 binary
// w1: [30, 2, 5, 5] fp32 ; w2: [100, 30, 5, 5] fp32
// pooled (post conv1+fire+pool, padded by 1): logical [32][131][131] x 30ch
// stored as bf16 [t][131][132][32]  (x padded to 132, ch padded to 32)
#define PB_H 131
#define PB_W 132
#define CI   32
#define POOL_ELEMS ((size_t)32 * PB_H * PB_W * CI)          // 17,707,008
#define POOL_BYTES (POOL_ELEMS * 2)                          // 35,414,016
#define W2R_BYTES  (5 * 5 * 112 * 32 * 2)                    // 179,200
#define N_POOL_PIX (32 * 129 * 129)                          // 532,898
#define CNT_BYTES  ((size_t)32 * 131 * 131)                  // 549,152
#define N_WIN      (32 * 127 * 127)                          // 516,128

// ws layout
#define OFF_POOL  ((size_t)0)
#define OFF_W2R   (OFF_POOL + POOL_BYTES)
#define OFF_W1P   (OFF_W2R + W2R_BYTES)                      // 960 uints = 3840 B
#define OFF_MN    (OFF_W1P + 3840)                           // 100 floats
#define OFF_MX    (OFF_MN + 400)                             // 100 floats
#define OFF_CNT   (OFF_MX + 400)
#define OFF_MAXS  (OFF_CNT + CNT_BYTES)                      // int
#define OFF_FLAG  (OFF_MAXS + 4)                             // int

// ---------------- kernel: repack w2 -> bf16 [ky][kx][112][32] (for fallback) ----------------
__global__ void repack_w2_kernel(const float* __restrict__ w2, bf16_t* __restrict__ w2r) {
    int idx = blockIdx.x * 256 + threadIdx.x;                // 0 .. 89599
    if (idx >= 5 * 5 * 112 * 32) return;
    int i  = idx & 31;
    int m  = (idx >> 5) % 112;
    int kk = idx / (112 * 32);
    int ky = kk / 5, kx = kk % 5;
    float v = 0.0f;
    if (m < 100 && i < 30) v = w2[((m * 30 + i) * 5 + ky) * 5 + kx];
    w2r[idx] = (bf16_t)v;
}

// ---------------- kernel: pack w1 -> f16 pairs [c][32 words], word = ci*15+ky*3+j ----------------
__global__ void w1pack_kernel(const float* __restrict__ w1, unsigned* __restrict__ w1p) {
    int idx = blockIdx.x * 256 + threadIdx.x;                // 0..959
    if (idx >= 30 * 32) return;
    int c = idx >> 5, w = idx & 31;
    unsigned word = 0;
    if (w < 30) {
        int ci = w / 15, r = w % 15, ky = r / 3, j = r % 3;
        float a = w1[(((c * 2) + ci) * 5 + ky) * 5 + 2 * j];
        float b = (2 * j + 1 < 5) ? w1[(((c * 2) + ci) * 5 + ky) * 5 + 2 * j + 1] : 0.0f;
        word = __builtin_bit_cast(unsigned, __builtin_amdgcn_cvt_pkrtz(a, b));
    }
    w1p[idx] = word;
}

// ---------------- kernel: per-channel min/max of w2 ----------------
__global__ void w2minmax_kernel(const float* __restrict__ w2, float* __restrict__ mn, float* __restrict__ mx) {
    int c = blockIdx.x;                                      // 0..99
    int l = threadIdx.x;                                     // 0..63
    float lo = 1e30f, hi = -1e30f;
    for (int i = l; i < 750; i += 64) {
        float v = w2[c * 750 + i];
        lo = fminf(lo, v); hi = fmaxf(hi, v);
    }
    #pragma unroll
    for (int off = 32; off; off >>= 1) {
        lo = fminf(lo, __shfl_xor(lo, off));
        hi = fmaxf(hi, __shfl_xor(hi, off));
    }
    if (l == 0) { mn[c] = lo; mx[c] = hi; }
}

// ---------------- kernel: conv1 (v_dot2_f32_f16) + fire(15) + maxpool(2,2,pad1) ----------------
__global__ __launch_bounds__(256) void conv1_pool_kernel(const float* __restrict__ in,
                                                         const unsigned* __restrict__ w1p,
                                                         bf16_t* __restrict__ pool,
                                                         unsigned char* __restrict__ cnt) {
    int idx = blockIdx.x * 256 + threadIdx.x;
    if (idx >= N_POOL_PIX) return;
    int t   = idx / (129 * 129);
    int rem = idx % (129 * 129);
    int py  = rem / 129, px = rem % 129;

    const float* inT = in + (size_t)t * 2 * 256 * 256;
    int rbase = 2 * py - 3;                                  // 6 rows rbase..rbase+5
    int cbase = 2 * px - 4;                                  // 8 cols cbase..cbase+7 (even)

    // packed f16 input pairs: pp[ci][row][phase][j]
    h2 pp[2][6][2][3];
    bool interior = (rbase >= 0) & (rbase + 5 <= 255) & (cbase >= 0) & (cbase + 7 <= 255);

    #pragma unroll
    for (int ci = 0; ci < 2; ++ci) {
        #pragma unroll
        for (int r = 0; r < 6; ++r) {
            float e[8];
            int iy = rbase + r;
            if (interior) {
                const float* rowp = inT + ((size_t)ci * 256 + iy) * 256 + cbase;
                float2 a = *(const float2*)(rowp + 0);
                float2 b = *(const float2*)(rowp + 2);
                float2 c = *(const float2*)(rowp + 4);
                float2 d = *(const float2*)(rowp + 6);
                e[0] = a.x; e[1] = a.y; e[2] = b.x; e[3] = b.y;
                e[4] = c.x; e[5] = c.y; e[6] = d.x; e[7] = d.y;
            } else {
                #pragma unroll
                for (int j = 0; j < 8; ++j) {
                    int ix = cbase + j;
                    bool ok = ((unsigned)iy < 256u) & ((unsigned)ix < 256u);
                    int cy = iy < 0 ? 0 : (iy > 255 ? 255 : iy);
                    int cx = ix < 0 ? 0 : (ix > 255 ? 255 : ix);
                    float v = inT[((size_t)ci * 256 + cy) * 256 + cx];
                    e[j] = ok ? v : 0.0f;
                }
            }
            // phase0 pairs: (e1,e2),(e3,e4),(e5,e6) ; phase1: (e2,e3),(e4,e5),(e6,e7)
            // (third pair's 2nd elem is zero-weighted)
            #pragma unroll
            for (int j = 0; j < 3; ++j) {
                pp[ci][r][0][j] = __builtin_amdgcn_cvt_pkrtz(e[1 + 2 * j], e[2 + 2 * j]);
                pp[ci][r][1][j] = __builtin_amdgcn_cvt_pkrtz(e[2 + 2 * j], e[3 + 2 * j]);
            }
        }
    }

    // position validity (conv output range 0..255)
    int sy0 = 2 * py - 1, sx0 = 2 * px - 1;
    bool vy0 = (unsigned)sy0 < 256u, vy1 = (unsigned)(sy0 + 1) < 256u;
    bool vx0 = (unsigned)sx0 < 256u, vx1 = (unsigned)(sx0 + 1) < 256u;
    bool v00 = vy0 & vx0, v01 = vy0 & vx1, v10 = vy1 & vx0, v11 = vy1 & vx1;

    unsigned mask = 0;
    #pragma unroll 1
    for (int c = 0; c < 30; ++c) {
        const unsigned* wcu = w1p + (c << 5);                // uniform -> s_load
        float p00 = 0.f, p01 = 0.f, p10 = 0.f, p11 = 0.f;
        #pragma unroll
        for (int ci = 0; ci < 2; ++ci)
            #pragma unroll
            for (int ky = 0; ky < 5; ++ky)
                #pragma unroll
                for (int j = 0; j < 3; ++j) {
                    h2 w = __builtin_bit_cast(h2, wcu[ci * 15 + ky * 3 + j]);
                    p00 = __builtin_amdgcn_fdot2(w, pp[ci][ky + 0][0][j], p00, false);
                    p01 = __builtin_amdgcn_fdot2(w, pp[ci][ky + 0][1][j], p01, false);
                    p10 = __builtin_amdgcn_fdot2(w, pp[ci][ky + 1][0][j], p10, false);
                    p11 = __builtin_amdgcn_fdot2(w, pp[ci][ky + 1][1][j], p11, false);
                }
        bool s = ((p00 > 15.0f) & v00) | ((p01 > 15.0f) & v01) |
                 ((p10 > 15.0f) & v10) | ((p11 > 15.0f) & v11);
        mask |= ((unsigned)s) << c;
    }

    // write 32 bf16 (30 real + 2 zero pad) = 64 B, interior of padded buffer
    unsigned words[16];
    #pragma unroll
    for (int i2 = 0; i2 < 16; ++i2) {
        unsigned lo = ((mask >> (2 * i2)) & 1u) ? 0x3F80u : 0u;
        unsigned hi = ((mask >> (2 * i2 + 1)) & 1u) ? 0x3F80u : 0u;
        words[i2] = lo | (hi << 16);
    }
    size_t base = (((size_t)t * PB_H + (py + 1)) * PB_W + (px + 1)) * CI;
    uint4* dst = (uint4*)(pool + base);
    dst[0] = make_uint4(words[0],  words[1],  words[2],  words[3]);
    dst[1] = make_uint4(words[4],  words[5],  words[6],  words[7]);
    dst[2] = make_uint4(words[8],  words[9],  words[10], words[11]);
    dst[3] = make_uint4(words[12], words[13], words[14], words[15]);

    cnt[(size_t)t * 131 * 131 + (py + 1) * 131 + (px + 1)] = (unsigned char)__popc(mask);
}

// ---------------- kernel: max over 5x5 windows of spike counts ----------------
__global__ __launch_bounds__(256) void winmax_kernel(const unsigned char* __restrict__ cnt,
                                                     int* __restrict__ maxS) {
    int idx = blockIdx.x * 256 + threadIdx.x;
    int s = 0;
    if (idx < N_WIN) {
        int t  = idx / (127 * 127);
        int r  = idx % (127 * 127);
        int oy = r / 127, ox = r % 127;
        const unsigned char* base = cnt + (size_t)t * 131 * 131 + oy * 131 + ox;
        #pragma unroll
        for (int dy = 0; dy < 5; ++dy)
            #pragma unroll
            for (int dx = 0; dx < 5; ++dx)
                s += base[dy * 131 + dx];
    }
    #pragma unroll
    for (int off = 32; off; off >>= 1) s = max(s, __shfl_xor(s, off));
    if ((threadIdx.x & 63) == 0) atomicMax(maxS, s);
}

// ---------------- kernel: decide per-channel via bounds ----------------
__global__ void decide_kernel(const float* __restrict__ mn, const float* __restrict__ mx,
                              const int* __restrict__ maxS, float* __restrict__ out,
                              int* __restrict__ flag) {
    int c = threadIdx.x;                                     // 1 block of 128
    if (c >= 100) return;
    float S = (float)(*maxS);
    // pot2 bounds over all windows (valid for nonneg-min / any-max weights)
    bool fire = (mn[c] >= 0.0f) && (S * mn[c] > 10.5f);      // margin >> fp rounding
    bool zero = (mx[c] <= 0.0f) || (S * mx[c] < 9.5f);
    if (fire) out[c] = 1.0f;
    if (!fire && !zero) atomicOr(flag, 1);                   // exact fallback needed
}

// ---------------- fallback: exact conv2 (implicit GEMM, bf16 MFMA) + fire(10) + any ----------------
__global__ __launch_bounds__(256, 2) void conv2_any_kernel(const bf16_t* __restrict__ pool,
                                                           const bf16_t* __restrict__ w2r,
                                                           float* __restrict__ out,
                                                           const int* __restrict__ flag) {
    if (*flag == 0) return;                                  // all channels proven by bounds

    __shared__ __align__(16) bf16_t Bt[5 * PB_W * CI];   // 42,240 B
    __shared__ __align__(16) bf16_t At[5 * 112 * 32];    // 35,840 B

    int bx = blockIdx.x;
    int t = bx / 127, oy = bx % 127;
    int tid = threadIdx.x;

    const bf16_t* bsrc = pool + ((size_t)t * PB_H + oy) * PB_W * CI;
    for (int off = tid * 8; off < 5 * PB_W * CI; off += 256 * 8)
        *(uint4*)(Bt + off) = *(const uint4*)(bsrc + off);

    int lane = tid & 63, wv = tid >> 6;
    int quad = lane >> 4, l15 = lane & 15;
    int n0 = wv * 32 + l15;

    f32x4 acc[7][2] = {};

    for (int ky = 0; ky < 5; ++ky) {
        __syncthreads();
        const bf16_t* asrc = w2r + (size_t)ky * (5 * 112 * 32);
        for (int off = tid * 8; off < 5 * 112 * 32; off += 256 * 8)
            *(uint4*)(At + off) = *(const uint4*)(asrc + off);
        __syncthreads();

        #pragma unroll
        for (int kx = 0; kx < 5; ++kx) {
            bf16x8 a[7], b[2];
            #pragma unroll
            for (int mt = 0; mt < 7; ++mt)
                a[mt] = *(const bf16x8*)(At + ((kx * 112 + mt * 16 + l15) * 32 + quad * 8));
            #pragma unroll
            for (int j = 0; j < 2; ++j) {
                int x = n0 + j * 16 + kx;
                b[j] = *(const bf16x8*)(Bt + ((ky * PB_W + x) * CI + quad * 8));
            }
            #pragma unroll
            for (int mt = 0; mt < 7; ++mt)
                #pragma unroll
                for (int j = 0; j < 2; ++j)
                    acc[mt][j] = __builtin_amdgcn_mfma_f32_16x16x32_bf16(a[mt], b[j], acc[mt][j], 0, 0, 0);
        }
    }

    int ox0 = n0, ox1 = n0 + 16;
    #pragma unroll
    for (int mt = 0; mt < 7; ++mt) {
        #pragma unroll
        for (int r = 0; r < 4; ++r) {
            int c = mt * 16 + quad * 4 + r;
            bool f0 = (acc[mt][0][r] > 10.0f) && (ox0 < 127);
            bool f1 = (acc[mt][1][r] > 10.0f) && (ox1 < 127);
            if (c < 100 && (f0 || f1)) out[c] = 1.0f;
        }
    }
}

// ---------------- launch ----------------
extern "C" void kernel_launch(void* const* d_in, const int* in_sizes, int n_in,
                              void* d_out, int out_size, void* d_ws, size_t ws_size,
                              hipStream_t stream) {
    const float* in = (const float*)d_in[0];
    const float* w1 = (const float*)d_in[1];
    const float* w2 = (const float*)d_in[2];
    float* out = (float*)d_out;

    char* ws = (char*)d_ws;
    bf16_t*        pool = (bf16_t*)(ws + OFF_POOL);
    bf16_t*        w2r  = (bf16_t*)(ws + OFF_W2R);
    unsigned*      w1p  = (unsigned*)(ws + OFF_W1P);
    float*         mn   = (float*)(ws + OFF_MN);
    float*         mx   = (float*)(ws + OFF_MX);
    unsigned char* cnt  = (unsigned char*)(ws + OFF_CNT);
    int*           maxS = (int*)(ws + OFF_MAXS);
    int*           flag = (int*)(ws + OFF_FLAG);

    (void)hipMemsetAsync(out, 0, 100 * sizeof(float), stream);
    (void)hipMemsetAsync(pool, 0, POOL_BYTES, stream);
    (void)hipMemsetAsync(cnt, 0, CNT_BYTES + 8, stream);     // cnt + maxS + flag

    repack_w2_kernel<<<(5 * 5 * 112 * 32 + 255) / 256, 256, 0, stream>>>(w2, w2r);
    w1pack_kernel<<<4, 256, 0, stream>>>(w1, w1p);
    w2minmax_kernel<<<100, 64, 0, stream>>>(w2, mn, mx);
    conv1_pool_kernel<<<(N_POOL_PIX + 255) / 256, 256, 0, stream>>>(in, w1p, pool, cnt);
    winmax_kernel<<<(N_WIN + 255) / 256, 256, 0, stream>>>(cnt, maxS);
    decide_kernel<<<1, 128, 0, stream>>>(mn, mx, maxS, out, flag);
    conv2_any_kernel<<<32 * 127, 256, 0, stream>>>(pool, w2r, out, flag);
}

// Round 4
// 174.641 us; speedup vs baseline: 2.0355x; 1.5208x over previous
//
#include <hip/hip_runtime.h>
#include <hip/hip_bf16.h>

typedef __bf16 bf16_t;
typedef bf16_t bf16x8 __attribute__((ext_vector_type(8)));
typedef float f32x4 __attribute__((ext_vector_type(4)));
typedef __fp16 h2 __attribute__((ext_vector_type(2)));   // matches cvt_pkrtz / fdot2

// ---------------- constants ----------------
// input: [32, 2, 256, 256] fp32 binary
// w1: [30, 2, 5, 5] fp32 ; w2: [100, 30, 5, 5] fp32
// pooled (post conv1+fire+pool, padded by 1): logical [32][131][131] x 30ch
// stored as bf16 [t][131][132][32]  (x padded to 132, ch padded to 32)
#define PB_H 131
#define PB_W 132
#define CI   32
#define POOL_ELEMS ((size_t)32 * PB_H * PB_W * CI)          // 17,707,008
#define POOL_BYTES (POOL_ELEMS * 2)                          // 35,414,016
#define W2R_BYTES  (5 * 5 * 112 * 32 * 2)                    // 179,200
#define CNT_BYTES  ((size_t)32 * 131 * 131)                  // 549,152
#define N_WIN      (32 * 127 * 127)                          // 516,128
#define N_BUCK     1024

// ws layout: [zero region: POOL | CNT | BUCKETS | FLAG] [W2R | W1P | MN | MX]
#define OFF_POOL  ((size_t)0)
#define OFF_CNT   (OFF_POOL + POOL_BYTES)
#define OFF_BUCK  (OFF_CNT + CNT_BYTES)
#define OFF_FLAG  (OFF_BUCK + N_BUCK * 4)
#define ZERO_BYTES (OFF_FLAG + 4)
#define OFF_W2R   ((ZERO_BYTES + 15) & ~(size_t)15)
#define OFF_W1P   (OFF_W2R + W2R_BYTES)                      // 960 uints = 3840 B
#define OFF_MN    (OFF_W1P + 3840)                           // 100 floats
#define OFF_MX    (OFF_MN + 400)                             // 100 floats

// ---------------- prep: repack w2 (bf16) + pack w1 (f16 pairs) + w2 min/max ----------------
__global__ __launch_bounds__(256) void prep_kernel(const float* __restrict__ w1,
                                                   const float* __restrict__ w2,
                                                   bf16_t* __restrict__ w2r,
                                                   unsigned* __restrict__ w1p,
                                                   float* __restrict__ mn,
                                                   float* __restrict__ mx) {
    int bx = blockIdx.x, tid = threadIdx.x;
    if (bx < 350) {
        // w2 -> bf16 [ky][kx][112][32]
        int idx = bx * 256 + tid;                            // 0 .. 89599
        int i  = idx & 31;
        int m  = (idx >> 5) % 112;
        int kk = idx / (112 * 32);
        int ky = kk / 5, kx = kk % 5;
        float v = 0.0f;
        if (m < 100 && i < 30) v = w2[((m * 30 + i) * 5 + ky) * 5 + kx];
        w2r[idx] = (bf16_t)v;
    } else if (bx < 354) {
        // w1 -> f16 pairs [c][32 words], word = ci*15 + ky*3 + j
        int idx = (bx - 350) * 256 + tid;                    // 0..1023
        if (idx < 30 * 32) {
            int c = idx >> 5, w = idx & 31;
            unsigned word = 0;
            if (w < 30) {
                int ci = w / 15, r = w % 15, ky = r / 3, j = r % 3;
                float a = w1[(((c * 2) + ci) * 5 + ky) * 5 + 2 * j];
                float b = (2 * j + 1 < 5) ? w1[(((c * 2) + ci) * 5 + ky) * 5 + 2 * j + 1] : 0.0f;
                word = __builtin_bit_cast(unsigned, __builtin_amdgcn_cvt_pkrtz(a, b));
            }
            w1p[idx] = word;
        }
    } else {
        // per-channel min/max of w2
        int c = bx - 354;                                    // 0..99
        float lo = 1e30f, hi = -1e30f;
        for (int i = tid; i < 750; i += 256) {
            float v = w2[c * 750 + i];
            lo = fminf(lo, v); hi = fmaxf(hi, v);
        }
        #pragma unroll
        for (int off = 32; off; off >>= 1) {
            lo = fminf(lo, __shfl_xor(lo, off));
            hi = fmaxf(hi, __shfl_xor(hi, off));
        }
        __shared__ float smn[4], smx[4];
        if ((tid & 63) == 0) { smn[tid >> 6] = lo; smx[tid >> 6] = hi; }
        __syncthreads();
        if (tid == 0) {
            mn[c] = fminf(fminf(smn[0], smn[1]), fminf(smn[2], smn[3]));
            mx[c] = fmaxf(fmaxf(smx[0], smx[1]), fmaxf(smx[2], smx[3]));
        }
    }
}

// ---------------- shared conv1 helpers ----------------
__device__ __forceinline__ unsigned conv1_channels(const unsigned* __restrict__ w1p,
                                                   const h2 pp[2][6][2][3],
                                                   bool v00, bool v01, bool v10, bool v11) {
    unsigned mask = 0;
    #pragma unroll 1
    for (int c = 0; c < 30; ++c) {
        const unsigned* wcu = w1p + (c << 5);                // uniform -> s_load
        float p00 = 0.f, p01 = 0.f, p10 = 0.f, p11 = 0.f;
        #pragma unroll
        for (int ci = 0; ci < 2; ++ci)
            #pragma unroll
            for (int ky = 0; ky < 5; ++ky)
                #pragma unroll
                for (int j = 0; j < 3; ++j) {
                    h2 w = __builtin_bit_cast(h2, wcu[ci * 15 + ky * 3 + j]);
                    p00 = __builtin_amdgcn_fdot2(w, pp[ci][ky + 0][0][j], p00, false);
                    p01 = __builtin_amdgcn_fdot2(w, pp[ci][ky + 0][1][j], p01, false);
                    p10 = __builtin_amdgcn_fdot2(w, pp[ci][ky + 1][0][j], p10, false);
                    p11 = __builtin_amdgcn_fdot2(w, pp[ci][ky + 1][1][j], p11, false);
                }
        bool s = ((p00 > 15.0f) & v00) | ((p01 > 15.0f) & v01) |
                 ((p10 > 15.0f) & v10) | ((p11 > 15.0f) & v11);
        mask |= ((unsigned)s) << c;
    }
    return mask;
}

__device__ __forceinline__ void conv1_store(bf16_t* __restrict__ pool,
                                            unsigned char* __restrict__ cnt,
                                            int t, int py, int px, unsigned mask) {
    unsigned words[16];
    #pragma unroll
    for (int i2 = 0; i2 < 16; ++i2) {
        unsigned lo = ((mask >> (2 * i2)) & 1u) ? 0x3F80u : 0u;
        unsigned hi = ((mask >> (2 * i2 + 1)) & 1u) ? 0x3F80u : 0u;
        words[i2] = lo | (hi << 16);
    }
    size_t base = (((size_t)t * PB_H + (py + 1)) * PB_W + (px + 1)) * CI;
    uint4* dst = (uint4*)(pool + base);
    dst[0] = make_uint4(words[0],  words[1],  words[2],  words[3]);
    dst[1] = make_uint4(words[4],  words[5],  words[6],  words[7]);
    dst[2] = make_uint4(words[8],  words[9],  words[10], words[11]);
    dst[3] = make_uint4(words[12], words[13], words[14], words[15]);
    cnt[(size_t)t * 131 * 131 + (py + 1) * 131 + (px + 1)] = (unsigned char)__popc(mask);
}

// pack one 8-float row segment into phase0/phase1 f16 pairs
__device__ __forceinline__ void pack_row(const float e[8], h2* ph0, h2* ph1) {
    #pragma unroll
    for (int j = 0; j < 3; ++j) {
        ph0[j] = __builtin_amdgcn_cvt_pkrtz(e[1 + 2 * j], e[2 + 2 * j]);
        ph1[j] = __builtin_amdgcn_cvt_pkrtz(e[2 + 2 * j], e[3 + 2 * j]);
    }
}

// ---------------- conv1 interior: py,px in [2,126] -> no bounds logic at all ----------------
__global__ __launch_bounds__(256) void conv1_interior_kernel(const float* __restrict__ in,
                                                             const unsigned* __restrict__ w1p,
                                                             bf16_t* __restrict__ pool,
                                                             unsigned char* __restrict__ cnt) {
    int t = blockIdx.y;
    int idx = blockIdx.x * 256 + threadIdx.x;
    if (idx >= 125 * 125) return;
    int py = idx / 125 + 2, px = idx % 125 + 2;

    const float* inT = in + (size_t)t * 2 * 256 * 256;
    int rbase = 2 * py - 3;                                  // 1..249
    int cbase = 2 * px - 4;                                  // 0..248

    h2 pp[2][6][2][3];
    #pragma unroll
    for (int ci = 0; ci < 2; ++ci) {
        #pragma unroll
        for (int r = 0; r < 6; ++r) {
            const float* rowp = inT + ((size_t)ci * 256 + (rbase + r)) * 256 + cbase;
            float2 a = *(const float2*)(rowp + 0);
            float2 b = *(const float2*)(rowp + 2);
            float2 c = *(const float2*)(rowp + 4);
            float2 d = *(const float2*)(rowp + 6);
            float e[8] = {a.x, a.y, b.x, b.y, c.x, c.y, d.x, d.y};
            pack_row(e, pp[ci][r][0], pp[ci][r][1]);
        }
    }

    unsigned mask = conv1_channels(w1p, pp, true, true, true, true);
    conv1_store(pool, cnt, t, py, px, mask);
}

// ---------------- conv1 border: the 1016 edge pixels per t, clamped path ----------------
__global__ __launch_bounds__(256) void conv1_border_kernel(const float* __restrict__ in,
                                                           const unsigned* __restrict__ w1p,
                                                           bf16_t* __restrict__ pool,
                                                           unsigned char* __restrict__ cnt) {
    int t = blockIdx.y;
    int bidx = blockIdx.x * 256 + threadIdx.x;               // 0..1023
    if (bidx >= 1016) return;
    int py, px;
    if (bidx < 516) {
        int rr = bidx / 129;                                 // 0..3
        py = (rr < 2) ? rr : 125 + rr;                       // {0,1,127,128}
        px = bidx % 129;
    } else {
        int r = bidx - 516;
        int cc = r / 125;                                    // 0..3
        px = (cc < 2) ? cc : 125 + cc;                       // {0,1,127,128}
        py = r % 125 + 2;                                    // 2..126
    }

    const float* inT = in + (size_t)t * 2 * 256 * 256;
    int rbase = 2 * py - 3;
    int cbase = 2 * px - 4;

    h2 pp[2][6][2][3];
    #pragma unroll
    for (int ci = 0; ci < 2; ++ci) {
        #pragma unroll
        for (int r = 0; r < 6; ++r) {
            int iy = rbase + r;
            float e[8];
            #pragma unroll
            for (int j = 0; j < 8; ++j) {
                int ix = cbase + j;
                bool ok = ((unsigned)iy < 256u) & ((unsigned)ix < 256u);
                int cy = iy < 0 ? 0 : (iy > 255 ? 255 : iy);
                int cx = ix < 0 ? 0 : (ix > 255 ? 255 : ix);
                float v = inT[((size_t)ci * 256 + cy) * 256 + cx];
                e[j] = ok ? v : 0.0f;
            }
            pack_row(e, pp[ci][r][0], pp[ci][r][1]);
        }
    }

    int sy0 = 2 * py - 1, sx0 = 2 * px - 1;
    bool vy0 = (unsigned)sy0 < 256u, vy1 = (unsigned)(sy0 + 1) < 256u;
    bool vx0 = (unsigned)sx0 < 256u, vx1 = (unsigned)(sx0 + 1) < 256u;

    unsigned mask = conv1_channels(w1p, pp, vy0 & vx0, vy0 & vx1, vy1 & vx0, vy1 & vx1);
    conv1_store(pool, cnt, t, py, px, mask);
}

// ---------------- winmax: max 5x5-window spike count, bucketed atomics ----------------
__global__ __launch_bounds__(256) void winmax_kernel(const unsigned char* __restrict__ cnt,
                                                     int* __restrict__ buckets) {
    int idx = blockIdx.x * 256 + threadIdx.x;
    int s = 0;
    if (idx < N_WIN) {
        int t  = idx / (127 * 127);
        int r  = idx % (127 * 127);
        int oy = r / 127, ox = r % 127;
        const unsigned char* base = cnt + (size_t)t * 131 * 131 + oy * 131 + ox;
        #pragma unroll
        for (int dy = 0; dy < 5; ++dy)
            #pragma unroll
            for (int dx = 0; dx < 5; ++dx)
                s += base[dy * 131 + dx];
    }
    #pragma unroll
    for (int off = 32; off; off >>= 1) s = max(s, __shfl_xor(s, off));
    __shared__ int sm[4];
    if ((threadIdx.x & 63) == 0) sm[threadIdx.x >> 6] = s;
    __syncthreads();
    if (threadIdx.x == 0) {
        int m = max(max(sm[0], sm[1]), max(sm[2], sm[3]));
        atomicMax(&buckets[blockIdx.x & (N_BUCK - 1)], m);   // <=2 blocks per bucket
    }
}

// ---------------- decide: reduce buckets, per-channel bounds, write all outputs ----------------
__global__ __launch_bounds__(256) void decide_kernel(const float* __restrict__ mn,
                                                     const float* __restrict__ mx,
                                                     const int* __restrict__ buckets,
                                                     float* __restrict__ out,
                                                     int* __restrict__ flag) {
    int tid = threadIdx.x;
    int m = 0;
    for (int i = tid; i < N_BUCK; i += 256) m = max(m, buckets[i]);
    #pragma unroll
    for (int off = 32; off; off >>= 1) m = max(m, __shfl_xor(m, off));
    __shared__ int sm[4];
    if ((tid & 63) == 0) sm[tid >> 6] = m;
    __syncthreads();
    int Si = max(max(sm[0], sm[1]), max(sm[2], sm[3]));
    if (tid < 100) {
        float S = (float)Si;
        // pot2 bounds over all windows (valid for nonneg-min / any-max weights)
        bool fire = (mn[tid] >= 0.0f) && (S * mn[tid] > 10.5f);  // margin >> fp rounding
        bool zero = (mx[tid] <= 0.0f) || (S * mx[tid] < 9.5f);
        out[tid] = fire ? 1.0f : 0.0f;
        if (!fire && !zero) atomicOr(flag, 1);               // exact fallback needed
    }
}

// ---------------- fallback: exact conv2 (implicit GEMM, bf16 MFMA) + fire(10) + any ----------------
__global__ __launch_bounds__(256, 2) void conv2_any_kernel(const bf16_t* __restrict__ pool,
                                                           const bf16_t* __restrict__ w2r,
                                                           float* __restrict__ out,
                                                           const int* __restrict__ flag) {
    if (*flag == 0) return;                                  // all channels proven by bounds

    __shared__ __align__(16) bf16_t Bt[5 * PB_W * CI];   // 42,240 B
    __shared__ __align__(16) bf16_t At[5 * 112 * 32];    // 35,840 B

    int bx = blockIdx.x;
    int t = bx / 127, oy = bx % 127;
    int tid = threadIdx.x;

    const bf16_t* bsrc = pool + ((size_t)t * PB_H + oy) * PB_W * CI;
    for (int off = tid * 8; off < 5 * PB_W * CI; off += 256 * 8)
        *(uint4*)(Bt + off) = *(const uint4*)(bsrc + off);

    int lane = tid & 63, wv = tid >> 6;
    int quad = lane >> 4, l15 = lane & 15;
    int n0 = wv * 32 + l15;

    f32x4 acc[7][2] = {};

    for (int ky = 0; ky < 5; ++ky) {
        __syncthreads();
        const bf16_t* asrc = w2r + (size_t)ky * (5 * 112 * 32);
        for (int off = tid * 8; off < 5 * 112 * 32; off += 256 * 8)
            *(uint4*)(At + off) = *(const uint4*)(asrc + off);
        __syncthreads();

        #pragma unroll
        for (int kx = 0; kx < 5; ++kx) {
            bf16x8 a[7], b[2];
            #pragma unroll
            for (int mt = 0; mt < 7; ++mt)
                a[mt] = *(const bf16x8*)(At + ((kx * 112 + mt * 16 + l15) * 32 + quad * 8));
            #pragma unroll
            for (int j = 0; j < 2; ++j) {
                int x = n0 + j * 16 + kx;
                b[j] = *(const bf16x8*)(Bt + ((ky * PB_W + x) * CI + quad * 8));
            }
            #pragma unroll
            for (int mt = 0; mt < 7; ++mt)
                #pragma unroll
                for (int j = 0; j < 2; ++j)
                    acc[mt][j] = __builtin_amdgcn_mfma_f32_16x16x32_bf16(a[mt], b[j], acc[mt][j], 0, 0, 0);
        }
    }

    int ox0 = n0, ox1 = n0 + 16;
    #pragma unroll
    for (int mt = 0; mt < 7; ++mt) {
        #pragma unroll
        for (int r = 0; r < 4; ++r) {
            int c = mt * 16 + quad * 4 + r;
            bool f0 = (acc[mt][0][r] > 10.0f) && (ox0 < 127);
            bool f1 = (acc[mt][1][r] > 10.0f) && (ox1 < 127);
            if (c < 100 && (f0 || f1)) out[c] = 1.0f;
        }
    }
}

// ---------------- launch ----------------
extern "C" void kernel_launch(void* const* d_in, const int* in_sizes, int n_in,
                              void* d_out, int out_size, void* d_ws, size_t ws_size,
                              hipStream_t stream) {
    const float* in = (const float*)d_in[0];
    const float* w1 = (const float*)d_in[1];
    const float* w2 = (const float*)d_in[2];
    float* out = (float*)d_out;

    char* ws = (char*)d_ws;
    bf16_t*        pool = (bf16_t*)(ws + OFF_POOL);
    unsigned char* cnt  = (unsigned char*)(ws + OFF_CNT);
    int*           buck = (int*)(ws + OFF_BUCK);
    int*           flag = (int*)(ws + OFF_FLAG);
    bf16_t*        w2r  = (bf16_t*)(ws + OFF_W2R);
    unsigned*      w1p  = (unsigned*)(ws + OFF_W1P);
    float*         mn   = (float*)(ws + OFF_MN);
    float*         mx   = (float*)(ws + OFF_MX);

    (void)hipMemsetAsync(ws, 0, ZERO_BYTES, stream);         // pool + cnt + buckets + flag

    prep_kernel<<<454, 256, 0, stream>>>(w1, w2, w2r, w1p, mn, mx);
    conv1_interior_kernel<<<dim3(62, 32), 256, 0, stream>>>(in, w1p, pool, cnt);
    conv1_border_kernel<<<dim3(4, 32), 256, 0, stream>>>(in, w1p, pool, cnt);
    winmax_kernel<<<(N_WIN + 255) / 256, 256, 0, stream>>>(cnt, buck);
    decide_kernel<<<1, 256, 0, stream>>>(mn, mx, buck, out, flag);
    conv2_any_kernel<<<32 * 127, 256, 0, stream>>>(pool, w2r, out, flag);
}

// Round 5
// 151.031 us; speedup vs baseline: 2.3537x; 1.1563x over previous
//
#include <hip/hip_runtime.h>
#include <hip/hip_bf16.h>

typedef __bf16 bf16_t;
typedef bf16_t bf16x8 __attribute__((ext_vector_type(8)));
typedef float f32x4 __attribute__((ext_vector_type(4)));
typedef float f32x4u __attribute__((ext_vector_type(4), aligned(4)));   // unaligned-safe
typedef unsigned u32x2u __attribute__((ext_vector_type(2), aligned(4)));

// ---------------- constants ----------------
// input: [32, 2, 256, 256] fp32 binary ; w1: [30,2,5,5] fp32 ; w2: [100,30,5,5] fp32
// pooled spikes stored as 30-bit masks: pmask [32][131][132] uint (padded ring = 0)
// cnt = popcount per pooled pixel, same [32][131][132] layout, bytes
#define PMASK_ELEMS ((size_t)32 * 131 * 132)                 // 553,344
#define PMASK_BYTES (PMASK_ELEMS * 4)                        // 2,213,376
#define CNT_BYTES   PMASK_ELEMS                              // 553,344
#define W2R_BYTES   (5 * 5 * 112 * 32 * 2)                   // 179,200
#define N_BUCK      1024

// ws layout: [zero: PMASK | CNT | BUCK | FLAG][W2R | W1F | MN | MX]
#define OFF_PMASK ((size_t)0)
#define OFF_CNT   (OFF_PMASK + PMASK_BYTES)
#define OFF_BUCK  (OFF_CNT + CNT_BYTES)
#define OFF_FLAG  (OFF_BUCK + N_BUCK * 4)
#define ZERO_BYTES (OFF_FLAG + 4)
#define OFF_W2R   ((ZERO_BYTES + 15) & ~(size_t)15)
#define OFF_W1F   (OFF_W2R + W2R_BYTES)                      // 2048 bf16 = 4 KB
#define OFF_MN    (OFF_W1F + 4096)
#define OFF_MX    (OFF_MN + 400)

// ---------------- prep: w2->bf16 repack, w1->MFMA A-fragments, w2 min/max ----------------
__global__ __launch_bounds__(256) void prep_kernel(const float* __restrict__ w1,
                                                   const float* __restrict__ w2,
                                                   bf16_t* __restrict__ w2r,
                                                   bf16_t* __restrict__ w1f,
                                                   float* __restrict__ mn,
                                                   float* __restrict__ mx) {
    int bx = blockIdx.x, tid = threadIdx.x;
    if (bx < 350) {
        // w2 -> bf16 [ky][kx][112][32]
        int idx = bx * 256 + tid;                            // 0..89599
        int i  = idx & 31;
        int m  = (idx >> 5) % 112;
        int kk = idx / (112 * 32);
        int ky = kk / 5, kx = kk % 5;
        float v = 0.0f;
        if (m < 100 && i < 30) v = w2[((m * 30 + i) * 5 + ky) * 5 + kx];
        w2r[idx] = (bf16_t)v;
    } else if (bx < 358) {
        // w1 -> packed A fragments: frag f=(ks*2+mt), lane l, elem j
        // element = A[m = (f&1)*16 + (l&15)][k = (f>>1)*32 + (l>>4)*8 + j], k = ci*25+ky*5+kx
        int idx = (bx - 350) * 256 + tid;                    // 0..2047
        int f = idx >> 9, l = (idx >> 3) & 63, j = idx & 7;
        int m = (f & 1) * 16 + (l & 15);
        int k = (f >> 1) * 32 + (l >> 4) * 8 + j;
        float v = (m < 30 && k < 50) ? w1[m * 50 + k] : 0.0f;
        w1f[idx] = (bf16_t)v;
    } else {
        // per-channel min/max of w2
        int c = bx - 358;                                    // 0..99
        float lo = 1e30f, hi = -1e30f;
        for (int i = tid; i < 750; i += 256) {
            float v = w2[c * 750 + i];
            lo = fminf(lo, v); hi = fmaxf(hi, v);
        }
        #pragma unroll
        for (int off = 32; off; off >>= 1) {
            lo = fminf(lo, __shfl_xor(lo, off));
            hi = fmaxf(hi, __shfl_xor(hi, off));
        }
        __shared__ float smn[4], smx[4];
        if ((tid & 63) == 0) { smn[tid >> 6] = lo; smx[tid >> 6] = hi; }
        __syncthreads();
        if (tid == 0) {
            mn[c] = fminf(fminf(smn[0], smn[1]), fminf(smn[2], smn[3]));
            mx[c] = fmaxf(fmaxf(smx[0], smx[1]), fmaxf(smx[2], smx[3]));
        }
    }
}

// pack two binary floats (0.0/1.0) into one uint of 2 bf16 (bit-exact: bf16 = fp32>>16)
__device__ __forceinline__ unsigned pk2(float a, float b) {
    return (__builtin_bit_cast(unsigned, a) >> 16) |
           (__builtin_bit_cast(unsigned, b) & 0xFFFF0000u);
}

// ---------------- conv1 via MFMA: block = (t, pooled row py) ----------------
// computes conv rows r0=2py-1, r1=2py (256 px each) as GEMM [M=32]x[K=64]x[N=512],
// fires(15), pools 2x2 -> pooled row py: pmask + cnt
__global__ __launch_bounds__(512, 4) void conv1_mfma_kernel(const float* __restrict__ in,
                                                            const bf16_t* __restrict__ w1f,
                                                            unsigned* __restrict__ pmask,
                                                            unsigned char* __restrict__ cnt) {
    __shared__ __align__(16) bf16_t Bs[512 * 64];            // 64 KB, XOR-swizzled 16B slots
    __shared__ __align__(16) bf16_t As[2048];                // 4 KB packed A-frags
    __shared__ unsigned Ms[512];                             // per-conv-pixel 30-bit fire masks

    int py = blockIdx.x;                                     // 0..128
    int t  = blockIdx.y;
    int tid = threadIdx.x;

    if (tid < 256) *(uint4*)(As + tid * 8) = *(const uint4*)(w1f + tid * 8);

    // ---- build im2col B: thread = one conv pixel (row rs, col px) ----
    int rs = tid >> 8, px = tid & 255;
    int r  = 2 * py - 1 + rs;                                // conv row, may be -1/256 -> zeros
    bool rv = (unsigned)r < 256u;
    const float* inT = in + (size_t)t * 2 * 256 * 256;

    unsigned u[25];
    float carry = 0.0f;
    bool fast = (px >= 2) & (px <= 253);
    #pragma unroll
    for (int ci = 0; ci < 2; ++ci) {
        #pragma unroll
        for (int ky = 0; ky < 5; ++ky) {
            int rr = r - 2 + ky;
            bool rrv = rv & ((unsigned)rr < 256u);
            const float* rowp = inT + ((size_t)ci * 256 + (rrv ? rr : 0)) * 256;
            float f0, f1, f2, f3, f4;
            if (fast) {
                f32x4u q = *(const f32x4u*)(rowp + (px - 2));
                float g = rowp[px + 2];
                f0 = rrv ? q.x : 0.f; f1 = rrv ? q.y : 0.f; f2 = rrv ? q.z : 0.f;
                f3 = rrv ? q.w : 0.f; f4 = rrv ? g : 0.f;
            } else {
                float e[5];
                #pragma unroll
                for (int kx = 0; kx < 5; ++kx) {
                    int cc = px - 2 + kx;
                    bool ok = rrv & ((unsigned)cc < 256u);
                    int cx = cc < 0 ? 0 : (cc > 255 ? 255 : cc);
                    float v = rowp[cx];
                    e[kx] = ok ? v : 0.0f;
                }
                f0 = e[0]; f1 = e[1]; f2 = e[2]; f3 = e[3]; f4 = e[4];
            }
            int i = ci * 5 + ky;                             // row index 0..9, k0 = i*5
            int k0 = i * 5;
            if ((i & 1) == 0) {
                u[k0 / 2]     = pk2(f0, f1);
                u[k0 / 2 + 1] = pk2(f2, f3);
                carry = f4;
            } else {
                u[(k0 - 1) / 2] = pk2(carry, f0);
                u[(k0 + 1) / 2] = pk2(f1, f2);
                u[(k0 + 3) / 2] = pk2(f3, f4);
            }
        }
    }

    // write 8 swizzled 16B slots (k 50..63 zero-padded)
    {
        int p = tid;
        uint4 s[8];
        s[0] = make_uint4(u[0],  u[1],  u[2],  u[3]);
        s[1] = make_uint4(u[4],  u[5],  u[6],  u[7]);
        s[2] = make_uint4(u[8],  u[9],  u[10], u[11]);
        s[3] = make_uint4(u[12], u[13], u[14], u[15]);
        s[4] = make_uint4(u[16], u[17], u[18], u[19]);
        s[5] = make_uint4(u[20], u[21], u[22], u[23]);
        s[6] = make_uint4(u[24], 0, 0, 0);
        s[7] = make_uint4(0, 0, 0, 0);
        #pragma unroll
        for (int sl = 0; sl < 8; ++sl)
            *(uint4*)(Bs + (size_t)p * 64 + ((sl ^ (p & 7)) << 3)) = s[sl];
    }
    __syncthreads();

    // ---- MFMA: wave w handles pixels (w>>2)*256 + (w&3)*64 + nt*16 + l15 ----
    int wv = tid >> 6, lane = tid & 63, quad = lane >> 4, l15 = lane & 15;
    int pbase = (wv >> 2) * 256 + (wv & 3) * 64;

    f32x4 acc[2][4] = {};
    #pragma unroll
    for (int ks = 0; ks < 2; ++ks) {
        bf16x8 a[2], b[4];
        #pragma unroll
        for (int mt = 0; mt < 2; ++mt)
            a[mt] = *(const bf16x8*)(As + ((ks * 2 + mt) * 64 + lane) * 8);
        #pragma unroll
        for (int nt = 0; nt < 4; ++nt) {
            int p = pbase + nt * 16 + l15;
            int slot = (ks * 4 + quad) ^ (p & 7);
            b[nt] = *(const bf16x8*)(Bs + (size_t)p * 64 + slot * 8);
        }
        #pragma unroll
        for (int mt = 0; mt < 2; ++mt)
            #pragma unroll
            for (int nt = 0; nt < 4; ++nt)
                acc[mt][nt] = __builtin_amdgcn_mfma_f32_16x16x32_bf16(a[mt], b[nt], acc[mt][nt], 0, 0, 0);
    }

    // ---- fire(15) -> per-pixel 30-bit mask (C layout: n=l15, m=quad*4+r) ----
    #pragma unroll
    for (int nt = 0; nt < 4; ++nt) {
        unsigned pm = 0;
        #pragma unroll
        for (int mt = 0; mt < 2; ++mt)
            #pragma unroll
            for (int rr = 0; rr < 4; ++rr) {
                int c = mt * 16 + quad * 4 + rr;
                if (acc[mt][nt][rr] > 15.0f) pm |= (1u << c);
            }
        pm |= __shfl_xor(pm, 16);
        pm |= __shfl_xor(pm, 32);
        pm &= 0x3FFFFFFFu;                                   // drop pad channels (zero anyway)
        if (quad == 0) Ms[pbase + nt * 16 + l15] = pm;
    }
    __syncthreads();

    // ---- pool 2x2 -> pooled row py ----
    if (tid < 129) {
        int c0 = 2 * tid - 1, c1 = 2 * tid;
        unsigned m = 0;
        if (c0 >= 0)  m |= Ms[c0] | Ms[256 + c0];
        if (c1 <= 255) m |= Ms[c1] | Ms[256 + c1];
        size_t o = ((size_t)t * 131 + (py + 1)) * 132 + (tid + 1);
        pmask[o] = m;
        cnt[o] = (unsigned char)__popc(m);
    }
}

// ---------------- winmax: max 5x5-window spike count, 4 windows/thread ----------------
__global__ __launch_bounds__(256) void winmax_kernel(const unsigned char* __restrict__ cnt,
                                                     int* __restrict__ buckets) {
    int idx = blockIdx.x * 256 + threadIdx.x;                // 32*127*32 = 130,048 exact
    int t   = idx / (127 * 32);
    int r   = idx % (127 * 32);
    int oy  = r >> 5;
    int ox0 = (r & 31) * 4;                                  // 0..124
    const unsigned char* base = cnt + ((size_t)t * 131 + oy) * 132 + ox0;
    int w0 = 0, w1 = 0, w2 = 0, w3 = 0;
    #pragma unroll
    for (int dy = 0; dy < 5; ++dy) {
        u32x2u d = *(const u32x2u*)(base + dy * 132);
        int b0 = d.x & 255, b1 = (d.x >> 8) & 255, b2 = (d.x >> 16) & 255, b3 = d.x >> 24;
        int b4 = d.y & 255, b5 = (d.y >> 8) & 255, b6 = (d.y >> 16) & 255, b7 = d.y >> 24;
        int s14 = b1 + b2 + b3 + b4;
        w0 += b0 + s14;
        w1 += s14 + b5;
        int s36 = b3 + b4 + b5 + b6;
        w2 += b2 + s36;
        w3 += s36 + b7;
    }
    int m = w0;                                              // ox0 <= 124 always valid
    if (ox0 + 1 <= 126) m = max(m, w1);
    if (ox0 + 2 <= 126) m = max(m, w2);
    if (ox0 + 3 <= 126) m = max(m, w3);
    #pragma unroll
    for (int off = 32; off; off >>= 1) m = max(m, __shfl_xor(m, off));
    __shared__ int sm[4];
    if ((threadIdx.x & 63) == 0) sm[threadIdx.x >> 6] = m;
    __syncthreads();
    if (threadIdx.x == 0) {
        int mm = max(max(sm[0], sm[1]), max(sm[2], sm[3]));
        atomicMax(&buckets[blockIdx.x & (N_BUCK - 1)], mm);  // <=1 block per bucket
    }
}

// ---------------- decide: reduce buckets, per-channel bounds ----------------
__global__ __launch_bounds__(256) void decide_kernel(const float* __restrict__ mn,
                                                     const float* __restrict__ mx,
                                                     const int* __restrict__ buckets,
                                                     float* __restrict__ out,
                                                     int* __restrict__ flag) {
    int tid = threadIdx.x;
    int m = 0;
    for (int i = tid; i < N_BUCK; i += 256) m = max(m, buckets[i]);
    #pragma unroll
    for (int off = 32; off; off >>= 1) m = max(m, __shfl_xor(m, off));
    __shared__ int sm[4];
    if ((tid & 63) == 0) sm[tid >> 6] = m;
    __syncthreads();
    int Si = max(max(sm[0], sm[1]), max(sm[2], sm[3]));
    if (tid < 100) {
        float S = (float)Si;
        bool fire = (mn[tid] >= 0.0f) && (S * mn[tid] > 10.5f);
        bool zero = (mx[tid] <= 0.0f) || (S * mx[tid] < 9.5f);
        out[tid] = fire ? 1.0f : 0.0f;
        if (!fire && !zero) atomicOr(flag, 1);               // exact fallback needed
    }
}

// ---------------- fallback: exact conv2 (bf16 MFMA) from pmask ----------------
__global__ __launch_bounds__(256, 2) void conv2_any_kernel(const unsigned* __restrict__ pmask,
                                                           const bf16_t* __restrict__ w2r,
                                                           float* __restrict__ out,
                                                           const int* __restrict__ flag) {
    if (*flag == 0) return;

    __shared__ __align__(16) bf16_t Bt[5 * 132 * 32];        // 42,240 B
    __shared__ __align__(16) bf16_t At[5 * 112 * 32];        // 35,840 B

    int bx = blockIdx.x;
    int t = bx / 127, oy = bx % 127;
    int tid = threadIdx.x;

    // expand pooled masks rows oy..oy+4 -> bf16 [row][x][32]
    for (int p = tid; p < 5 * 132; p += 256) {
        int row = p / 132, x = p % 132;
        unsigned m = pmask[((size_t)t * 131 + oy + row) * 132 + x];
        uint4* dst = (uint4*)(Bt + (size_t)p * 32);
        #pragma unroll
        for (int g = 0; g < 4; ++g) {
            unsigned ws[4];
            #pragma unroll
            for (int q = 0; q < 4; ++q) {
                int i2 = g * 4 + q;
                unsigned lo = ((m >> (2 * i2)) & 1u) ? 0x3F80u : 0u;
                unsigned hi = ((m >> (2 * i2 + 1)) & 1u) ? 0x3F80u : 0u;
                ws[q] = lo | (hi << 16);
            }
            dst[g] = make_uint4(ws[0], ws[1], ws[2], ws[3]);
        }
    }

    int lane = tid & 63, wv = tid >> 6;
    int quad = lane >> 4, l15 = lane & 15;
    int n0 = wv * 32 + l15;

    f32x4 acc[7][2] = {};

    for (int ky = 0; ky < 5; ++ky) {
        __syncthreads();
        const bf16_t* asrc = w2r + (size_t)ky * (5 * 112 * 32);
        for (int off = tid * 8; off < 5 * 112 * 32; off += 256 * 8)
            *(uint4*)(At + off) = *(const uint4*)(asrc + off);
        __syncthreads();

        #pragma unroll
        for (int kx = 0; kx < 5; ++kx) {
            bf16x8 a[7], b[2];
            #pragma unroll
            for (int mt = 0; mt < 7; ++mt)
                a[mt] = *(const bf16x8*)(At + ((kx * 112 + mt * 16 + l15) * 32 + quad * 8));
            #pragma unroll
            for (int j = 0; j < 2; ++j) {
                int x = n0 + j * 16 + kx;
                b[j] = *(const bf16x8*)(Bt + ((ky * 132 + x) * 32 + quad * 8));
            }
            #pragma unroll
            for (int mt = 0; mt < 7; ++mt)
                #pragma unroll
                for (int j = 0; j < 2; ++j)
                    acc[mt][j] = __builtin_amdgcn_mfma_f32_16x16x32_bf16(a[mt], b[j], acc[mt][j], 0, 0, 0);
        }
    }

    int ox0 = n0, ox1 = n0 + 16;
    #pragma unroll
    for (int mt = 0; mt < 7; ++mt) {
        #pragma unroll
        for (int r = 0; r < 4; ++r) {
            int c = mt * 16 + quad * 4 + r;
            bool f0 = (acc[mt][0][r] > 10.0f) && (ox0 < 127);
            bool f1 = (acc[mt][1][r] > 10.0f) && (ox1 < 127);
            if (c < 100 && (f0 || f1)) out[c] = 1.0f;
        }
    }
}

// ---------------- launch ----------------
extern "C" void kernel_launch(void* const* d_in, const int* in_sizes, int n_in,
                              void* d_out, int out_size, void* d_ws, size_t ws_size,
                              hipStream_t stream) {
    const float* in = (const float*)d_in[0];
    const float* w1 = (const float*)d_in[1];
    const float* w2 = (const float*)d_in[2];
    float* out = (float*)d_out;

    char* ws = (char*)d_ws;
    unsigned*      pmask = (unsigned*)(ws + OFF_PMASK);
    unsigned char* cnt   = (unsigned char*)(ws + OFF_CNT);
    int*           buck  = (int*)(ws + OFF_BUCK);
    int*           flag  = (int*)(ws + OFF_FLAG);
    bf16_t*        w2r   = (bf16_t*)(ws + OFF_W2R);
    bf16_t*        w1f   = (bf16_t*)(ws + OFF_W1F);
    float*         mn    = (float*)(ws + OFF_MN);
    float*         mx    = (float*)(ws + OFF_MX);

    (void)hipMemsetAsync(ws, 0, ZERO_BYTES, stream);         // pmask + cnt + buckets + flag

    prep_kernel<<<458, 256, 0, stream>>>(w1, w2, w2r, w1f, mn, mx);
    conv1_mfma_kernel<<<dim3(129, 32), 512, 0, stream>>>(in, w1f, pmask, cnt);
    winmax_kernel<<<508, 256, 0, stream>>>(cnt, buck);
    decide_kernel<<<1, 256, 0, stream>>>(mn, mx, buck, out, flag);
    conv2_any_kernel<<<32 * 127, 256, 0, stream>>>(pmask, w2r, out, flag);
}

// Round 6
// 101.288 us; speedup vs baseline: 3.5095x; 1.4911x over previous
//
#include <hip/hip_runtime.h>
#include <hip/hip_bf16.h>

typedef __bf16 bf16_t;
typedef bf16_t bf16x8 __attribute__((ext_vector_type(8)));
typedef bf16_t bf16x8a4 __attribute__((ext_vector_type(8), aligned(4)));
typedef float f32x4 __attribute__((ext_vector_type(4)));
typedef unsigned u32x2u __attribute__((ext_vector_type(2), aligned(4)));

// ---------------- constants ----------------
// input: [32, 2, 256, 256] fp32 binary ; w1: [30,2,5,5] fp32 ; w2: [100,30,5,5] fp32
// pooled spikes stored as 30-bit masks: pmask [32][131][132] uint (padded ring = 0)
// cnt = popcount per pooled pixel, same layout, bytes
#define PMASK_ELEMS ((size_t)32 * 131 * 132)                 // 553,344
#define PMASK_BYTES (PMASK_ELEMS * 4)
#define CNT_BYTES   PMASK_ELEMS
#define W2R_BYTES   (5 * 5 * 112 * 32 * 2)                   // 179,200
#define W1F_ELEMS   (6 * 512)                                // 3072 bf16 (A-fragments)
#define N_BUCK      1024

// ws layout: [zero: PMASK | CNT | BUCK | FLAG][W2R | W1F | MN | MX]
#define OFF_PMASK ((size_t)0)
#define OFF_CNT   (OFF_PMASK + PMASK_BYTES)
#define OFF_BUCK  (OFF_CNT + CNT_BYTES)
#define OFF_FLAG  (OFF_BUCK + N_BUCK * 4)
#define ZERO_BYTES (OFF_FLAG + 4)
#define OFF_W2R   ((ZERO_BYTES + 15) & ~(size_t)15)
#define OFF_W1F   (OFF_W2R + W2R_BYTES)
#define OFF_MN    (OFF_W1F + W1F_ELEMS * 2 + 64)
#define OFF_MX    (OFF_MN + 400)

// ---------------- prep: w2->bf16, w1->A-fragments (k = row*8+tap), w2 min/max ----------------
__global__ __launch_bounds__(256) void prep_kernel(const float* __restrict__ w1,
                                                   const float* __restrict__ w2,
                                                   bf16_t* __restrict__ w2r,
                                                   bf16_t* __restrict__ w1f,
                                                   float* __restrict__ mn,
                                                   float* __restrict__ mx) {
    int bx = blockIdx.x, tid = threadIdx.x;
    if (bx < 350) {
        // w2 -> bf16 [ky][kx][112][32]
        int idx = bx * 256 + tid;                            // 0..89599
        int i  = idx & 31;
        int m  = (idx >> 5) % 112;
        int kk = idx / (112 * 32);
        int ky = kk / 5, kx = kk % 5;
        float v = 0.0f;
        if (m < 100 && i < 30) v = w2[((m * 30 + i) * 5 + ky) * 5 + kx];
        w2r[idx] = (bf16_t)v;
    } else if (bx < 362) {
        // w1 A-fragments: frag f = ks*2+mt, lane l, elem j
        // m = (f&1)*16 + (l&15); row i = (f>>1)*4 + (l>>4); tap j
        // A[m][i*8+j] = w1[m*50 + i*5 + j] if (m<30 && i<10 && j<5) else 0
        int idx = (bx - 350) * 256 + tid;                    // 0..3071
        int f = idx >> 9, l = (idx >> 3) & 63, j = idx & 7;
        int m = (f & 1) * 16 + (l & 15);
        int i = (f >> 1) * 4 + (l >> 4);
        float v = (m < 30 && i < 10 && j < 5) ? w1[m * 50 + i * 5 + j] : 0.0f;
        w1f[idx] = (bf16_t)v;
    } else {
        // per-channel min/max of w2
        int c = bx - 362;                                    // 0..99
        float lo = 1e30f, hi = -1e30f;
        for (int i = tid; i < 750; i += 256) {
            float v = w2[c * 750 + i];
            lo = fminf(lo, v); hi = fmaxf(hi, v);
        }
        #pragma unroll
        for (int off = 32; off; off >>= 1) {
            lo = fminf(lo, __shfl_xor(lo, off));
            hi = fmaxf(hi, __shfl_xor(hi, off));
        }
        __shared__ float smn[4], smx[4];
        if ((tid & 63) == 0) { smn[tid >> 6] = lo; smx[tid >> 6] = hi; }
        __syncthreads();
        if (tid == 0) {
            mn[c] = fminf(fminf(smn[0], smn[1]), fminf(smn[2], smn[3]));
            mx[c] = fmaxf(fmaxf(smx[0], smx[1]), fmaxf(smx[2], smx[3]));
        }
    }
}

// pack two binary floats (0.0/1.0) into one uint of 2 bf16 (exact: bf16 = fp32>>16)
__device__ __forceinline__ unsigned pk2(float a, float b) {
    return (__builtin_bit_cast(unsigned, a) >> 16) |
           (__builtin_bit_cast(unsigned, b) & 0xFFFF0000u);
}

// ---------------- conv1 via MFMA, zero-im2col ----------------
// Block = (t, 4 pooled rows py0..py0+3). LDS holds 24 raw input rows as dual-phase
// packed bf16 pairs: phase0 word w = (x=2w-4, 2w-3); phase1 word w = (x=2w-3, 2w-2).
// B-fragment for pixel p, row i = 4 consecutive words starting at (p+2-phi)/2 -> taps x=p-2..p+5
// (taps 5..7 carry zero A-weights). Wave wv computes pooled row py0+wv end-to-end.
#define ROW_W 136                                            // words per phase (pad incl.)
__global__ __launch_bounds__(256, 4) void conv1_mfma_kernel(const float* __restrict__ in,
                                                            const bf16_t* __restrict__ w1f,
                                                            unsigned* __restrict__ pmask,
                                                            unsigned char* __restrict__ cnt) {
    __shared__ __align__(16) unsigned Brows[24 * 2 * ROW_W]; // 26,112 B
    __shared__ __align__(16) unsigned Ms[4][2][256];         // 8 KB

    int py0 = blockIdx.x * 4;
    int t   = blockIdx.y;
    int tid = threadIdx.x;
    int lane = tid & 63, wv = tid >> 6;

    // A fragments -> registers (coalesced 16B loads)
    bf16x8 afr[3][2];
    #pragma unroll
    for (int ks = 0; ks < 3; ++ks)
        #pragma unroll
        for (int mt = 0; mt < 2; ++mt)
            afr[ks][mt] = *(const bf16x8*)(w1f + ((ks * 2 + mt) * 64 + lane) * 8);

    // zero edge words: per row phase0 {0,1,130..135}, phase1 {0,130..135}
    for (int z = tid; z < 24 * 15; z += 256) {
        int row = z / 15, e = z % 15;
        int w;
        if (e < 8) w = (e < 2) ? e : (128 + e);
        else { int e2 = e - 8; w = ROW_W + ((e2 == 0) ? 0 : (129 + e2)); }
        Brows[row * (2 * ROW_W) + w] = 0;
    }

    // stage 24 rows (2 ci x 12), coalesced, each float loaded once
    const float* inT = in + (size_t)t * 2 * 65536;
    #pragma unroll
    for (int k = 0; k < 6; ++k) {
        int seg = tid + k * 256;                             // 0..1535
        int row = seg >> 6, o = seg & 63;
        int ci = row / 12, s = row % 12;
        int iy = 2 * py0 - 3 + s;
        bool rv = (unsigned)iy < 256u;
        const float* rp = inT + ((size_t)ci * 256 + (rv ? iy : 0)) * 256 + 4 * o;
        f32x4 q = *(const f32x4*)rp;
        float v4 = (o < 63) ? rp[4] : 0.0f;
        if (!rv) { q = (f32x4){0.f, 0.f, 0.f, 0.f}; v4 = 0.0f; }
        unsigned base = row * (2 * ROW_W);
        int w = 2 * o + 2;
        *(uint2*)&Brows[base + w]         = make_uint2(pk2(q.x, q.y), pk2(q.z, q.w));
        *(uint2*)&Brows[base + ROW_W + w] = make_uint2(pk2(q.y, q.z), pk2(q.w, v4));
        if (o == 0) Brows[base + ROW_W + 1] = pk2(0.0f, q.x);
    }
    __syncthreads();

    // lane constants: phase + base word + per-ks row offset
    int quad = lane >> 4, l15 = lane & 15;
    int phi = l15 & 1;
    int baseW = 1 + (l15 >> 1);                              // (l15 + 2 - phi) >> 1
    int LC[3];
    #pragma unroll
    for (int ks = 0; ks < 3; ++ks) {
        int i = ks * 4 + quad;
        int cii = (i < 10) ? ((i < 5) ? 0 : 1) : 0;          // pad rows -> row 0 (A=0)
        int kyi = (i < 10) ? ((i < 5) ? i : i - 5) : 0;
        LC[ks] = (cii * 12 + kyi) * (2 * ROW_W) + phi * ROW_W + baseW;
    }

    int py = py0 + wv;                                       // this wave's pooled row
    #pragma unroll
    for (int rs01 = 0; rs01 < 2; ++rs01) {
        int r = 2 * py - 1 + rs01;                           // conv row (may be -1/256+)
        unsigned vmask = ((unsigned)r < 256u) ? 0x3FFFFFFFu : 0u;
        int rbase = (2 * wv + rs01) * (2 * ROW_W);
        #pragma unroll 4
        for (int ptile = 0; ptile < 16; ++ptile) {
            f32x4 acc[2] = {};
            #pragma unroll
            for (int ks = 0; ks < 3; ++ks) {
                bf16x8 b = __builtin_bit_cast(bf16x8,
                    *(const bf16x8a4*)&Brows[LC[ks] + rbase + ptile * 8]);
                #pragma unroll
                for (int mt = 0; mt < 2; ++mt)
                    acc[mt] = __builtin_amdgcn_mfma_f32_16x16x32_bf16(afr[ks][mt], b, acc[mt], 0, 0, 0);
            }
            unsigned pm = 0;
            #pragma unroll
            for (int mt = 0; mt < 2; ++mt)
                #pragma unroll
                for (int rr = 0; rr < 4; ++rr)
                    if (acc[mt][rr] > 15.0f) pm |= 1u << (mt * 16 + quad * 4 + rr);
            pm |= __shfl_xor(pm, 16);
            pm |= __shfl_xor(pm, 32);
            pm &= vmask;
            if (quad == 0) Ms[wv][rs01][ptile * 16 + l15] = pm;
        }
    }

    // pool 2x2 -> pooled row py (per-wave, no barrier needed)
    if (py <= 128) {
        for (int px = lane; px < 129; px += 64) {
            int c0 = 2 * px - 1, c1 = 2 * px;
            unsigned m = 0;
            if (c0 >= 0)  m |= Ms[wv][0][c0] | Ms[wv][1][c0];
            if (c1 <= 255) m |= Ms[wv][0][c1] | Ms[wv][1][c1];
            size_t o = ((size_t)t * 131 + (py + 1)) * 132 + (px + 1);
            pmask[o] = m;
            cnt[o] = (unsigned char)__popc(m);
        }
    }
}

// ---------------- winmax: max 5x5-window spike count, 4 windows/thread ----------------
__global__ __launch_bounds__(256) void winmax_kernel(const unsigned char* __restrict__ cnt,
                                                     int* __restrict__ buckets) {
    int idx = blockIdx.x * 256 + threadIdx.x;                // 32*127*32 = 130,048 exact
    int t   = idx / (127 * 32);
    int r   = idx % (127 * 32);
    int oy  = r >> 5;
    int ox0 = (r & 31) * 4;                                  // 0..124
    const unsigned char* base = cnt + ((size_t)t * 131 + oy) * 132 + ox0;
    int w0 = 0, w1 = 0, w2 = 0, w3 = 0;
    #pragma unroll
    for (int dy = 0; dy < 5; ++dy) {
        u32x2u d = *(const u32x2u*)(base + dy * 132);
        int b0 = d.x & 255, b1 = (d.x >> 8) & 255, b2 = (d.x >> 16) & 255, b3 = d.x >> 24;
        int b4 = d.y & 255, b5 = (d.y >> 8) & 255, b6 = (d.y >> 16) & 255, b7 = d.y >> 24;
        int s14 = b1 + b2 + b3 + b4;
        w0 += b0 + s14;
        w1 += s14 + b5;
        int s36 = b3 + b4 + b5 + b6;
        w2 += b2 + s36;
        w3 += s36 + b7;
    }
    int m = w0;
    if (ox0 + 1 <= 126) m = max(m, w1);
    if (ox0 + 2 <= 126) m = max(m, w2);
    if (ox0 + 3 <= 126) m = max(m, w3);
    #pragma unroll
    for (int off = 32; off; off >>= 1) m = max(m, __shfl_xor(m, off));
    __shared__ int sm[4];
    if ((threadIdx.x & 63) == 0) sm[threadIdx.x >> 6] = m;
    __syncthreads();
    if (threadIdx.x == 0) {
        int mm = max(max(sm[0], sm[1]), max(sm[2], sm[3]));
        atomicMax(&buckets[blockIdx.x & (N_BUCK - 1)], mm);
    }
}

// ---------------- decide: reduce buckets, per-channel bounds ----------------
__global__ __launch_bounds__(256) void decide_kernel(const float* __restrict__ mn,
                                                     const float* __restrict__ mx,
                                                     const int* __restrict__ buckets,
                                                     float* __restrict__ out,
                                                     int* __restrict__ flag) {
    int tid = threadIdx.x;
    int m = 0;
    for (int i = tid; i < N_BUCK; i += 256) m = max(m, buckets[i]);
    #pragma unroll
    for (int off = 32; off; off >>= 1) m = max(m, __shfl_xor(m, off));
    __shared__ int sm[4];
    if ((tid & 63) == 0) sm[tid >> 6] = m;
    __syncthreads();
    int Si = max(max(sm[0], sm[1]), max(sm[2], sm[3]));
    if (tid < 100) {
        float S = (float)Si;
        bool fire = (mn[tid] >= 0.0f) && (S * mn[tid] > 10.5f);
        bool zero = (mx[tid] <= 0.0f) || (S * mx[tid] < 9.5f);
        out[tid] = fire ? 1.0f : 0.0f;
        if (!fire && !zero) atomicOr(flag, 1);               // exact fallback needed
    }
}

// ---------------- fallback: exact conv2 (bf16 MFMA) from pmask, 508 blocks x 8 t ----------------
__global__ __launch_bounds__(256, 2) void conv2_any_kernel(const unsigned* __restrict__ pmask,
                                                           const bf16_t* __restrict__ w2r,
                                                           float* __restrict__ out,
                                                           const int* __restrict__ flag) {
    if (*flag == 0) return;                                  // proven by bounds: exit fast

    __shared__ __align__(16) bf16_t Bt[5 * 132 * 32];
    __shared__ __align__(16) bf16_t At[5 * 112 * 32];

    int oy = blockIdx.x % 127, tg = blockIdx.x / 127;
    int tid = threadIdx.x;
    int lane = tid & 63, wvv = tid >> 6;
    int quad = lane >> 4, l15 = lane & 15;
    int n0 = wvv * 32 + l15;

    for (int it = 0; it < 8; ++it) {
        int t = tg * 8 + it;
        __syncthreads();                                     // prior iter consumers done

        for (int p = tid; p < 5 * 132; p += 256) {
            int row = p / 132, x = p % 132;
            unsigned m = pmask[((size_t)t * 131 + oy + row) * 132 + x];
            uint4* dst = (uint4*)(Bt + (size_t)p * 32);
            #pragma unroll
            for (int g = 0; g < 4; ++g) {
                unsigned ws[4];
                #pragma unroll
                for (int q = 0; q < 4; ++q) {
                    int i2 = g * 4 + q;
                    unsigned lo = ((m >> (2 * i2)) & 1u) ? 0x3F80u : 0u;
                    unsigned hi = ((m >> (2 * i2 + 1)) & 1u) ? 0x3F80u : 0u;
                    ws[q] = lo | (hi << 16);
                }
                dst[g] = make_uint4(ws[0], ws[1], ws[2], ws[3]);
            }
        }

        f32x4 acc[7][2] = {};
        for (int ky = 0; ky < 5; ++ky) {
            __syncthreads();
            const bf16_t* asrc = w2r + (size_t)ky * (5 * 112 * 32);
            for (int off = tid * 8; off < 5 * 112 * 32; off += 256 * 8)
                *(uint4*)(At + off) = *(const uint4*)(asrc + off);
            __syncthreads();

            #pragma unroll
            for (int kx = 0; kx < 5; ++kx) {
                bf16x8 a[7], b[2];
                #pragma unroll
                for (int mt = 0; mt < 7; ++mt)
                    a[mt] = *(const bf16x8*)(At + ((kx * 112 + mt * 16 + l15) * 32 + quad * 8));
                #pragma unroll
                for (int j = 0; j < 2; ++j) {
                    int x = n0 + j * 16 + kx;
                    b[j] = *(const bf16x8*)(Bt + ((ky * 132 + x) * 32 + quad * 8));
                }
                #pragma unroll
                for (int mt = 0; mt < 7; ++mt)
                    #pragma unroll
                    for (int j = 0; j < 2; ++j)
                        acc[mt][j] = __builtin_amdgcn_mfma_f32_16x16x32_bf16(a[mt], b[j], acc[mt][j], 0, 0, 0);
            }
        }

        int ox0 = n0, ox1 = n0 + 16;
        #pragma unroll
        for (int mt = 0; mt < 7; ++mt) {
            #pragma unroll
            for (int r = 0; r < 4; ++r) {
                int c = mt * 16 + quad * 4 + r;
                bool f0 = (acc[mt][0][r] > 10.0f) && (ox0 < 127);
                bool f1 = (acc[mt][1][r] > 10.0f) && (ox1 < 127);
                if (c < 100 && (f0 || f1)) out[c] = 1.0f;
            }
        }
    }
}

// ---------------- launch ----------------
extern "C" void kernel_launch(void* const* d_in, const int* in_sizes, int n_in,
                              void* d_out, int out_size, void* d_ws, size_t ws_size,
                              hipStream_t stream) {
    const float* in = (const float*)d_in[0];
    const float* w1 = (const float*)d_in[1];
    const float* w2 = (const float*)d_in[2];
    float* out = (float*)d_out;

    char* ws = (char*)d_ws;
    unsigned*      pmask = (unsigned*)(ws + OFF_PMASK);
    unsigned char* cnt   = (unsigned char*)(ws + OFF_CNT);
    int*           buck  = (int*)(ws + OFF_BUCK);
    int*           flag  = (int*)(ws + OFF_FLAG);
    bf16_t*        w2r   = (bf16_t*)(ws + OFF_W2R);
    bf16_t*        w1f   = (bf16_t*)(ws + OFF_W1F);
    float*         mn    = (float*)(ws + OFF_MN);
    float*         mx    = (float*)(ws + OFF_MX);

    (void)hipMemsetAsync(ws, 0, ZERO_BYTES, stream);         // pmask + cnt + buckets + flag

    prep_kernel<<<462, 256, 0, stream>>>(w1, w2, w2r, w1f, mn, mx);
    conv1_mfma_kernel<<<dim3(33, 32), 256, 0, stream>>>(in, w1f, pmask, cnt);
    winmax_kernel<<<508, 256, 0, stream>>>(cnt, buck);
    decide_kernel<<<1, 256, 0, stream>>>(mn, mx, buck, out, flag);
    conv2_any_kernel<<<508, 256, 0, stream>>>(pmask, w2r, out, flag);
}

// Round 7
// 98.914 us; speedup vs baseline: 3.5938x; 1.0240x over previous
//
#include <hip/hip_runtime.h>
#include <hip/hip_bf16.h>

typedef __bf16 bf16_t;
typedef bf16_t bf16x8 __attribute__((ext_vector_type(8)));
typedef bf16_t bf16x8a4 __attribute__((ext_vector_type(8), aligned(4)));
typedef float f32x4 __attribute__((ext_vector_type(4)));
typedef unsigned u32x2u __attribute__((ext_vector_type(2), aligned(4)));

// ---------------- constants ----------------
// input: [32, 2, 256, 256] fp32 binary ; w1: [30,2,5,5] fp32 ; w2: [100,30,5,5] fp32
// pooled spikes as 30-bit masks: pmask [32][131][132] uint (ring zeroed by aux blocks)
// cnt = popcount per pooled pixel, same layout, bytes
#define PMASK_ELEMS ((size_t)32 * 131 * 132)                 // 553,344
#define PMASK_BYTES (PMASK_ELEMS * 4)
#define CNT_BYTES   PMASK_ELEMS
#define W2R_ELEMS   (5 * 5 * 112 * 32)                       // 89,600
#define N_WM_BLK    508                                      // winmax blocks

// ws layout (no zero-init required anywhere)
#define OFF_PMASK ((size_t)0)
#define OFF_CNT   (OFF_PMASK + PMASK_BYTES)
#define OFF_BUCK  ((OFF_CNT + CNT_BYTES + 15) & ~(size_t)15)
#define OFF_UNPR  (OFF_BUCK + 2048)
#define OFF_W2R   (OFF_UNPR + 512)

// pack two binary floats (0.0/1.0) into one uint of 2 bf16 (exact: bf16 = fp32>>16)
__device__ __forceinline__ unsigned pk2(float a, float b) {
    return (__builtin_bit_cast(unsigned, a) >> 16) |
           (__builtin_bit_cast(unsigned, b) & 0xFFFF0000u);
}

// ---------------- conv1 via MFMA, zero-im2col; aux blocks do ring-zero + w2 repack ----------------
// Conv blocks (bx<33) = (t, 4 pooled rows). LDS: 24 raw input rows as dual-phase packed
// bf16 pairs; B-fragment for pixel p, row i = 4 consecutive words (taps x=p-2..p+5, taps
// 5..7 carry zero A-weights, k = row*8+tap). Wave wv computes pooled row py0+wv end-to-end.
// A-fragments gathered inline from w1 (L2-broadcast).
#define ROW_W 136                                            // words per phase (pad incl.)
__global__ __launch_bounds__(256, 4) void conv1_mfma_kernel(const float* __restrict__ in,
                                                            const float* __restrict__ w1,
                                                            const float* __restrict__ w2,
                                                            unsigned* __restrict__ pmask,
                                                            unsigned char* __restrict__ cnt,
                                                            bf16_t* __restrict__ w2r) {
    int bx = blockIdx.x;
    int t  = blockIdx.y;
    int tid = threadIdx.x;

    if (bx == 33) {
        // ---- aux block: zero pmask/cnt ring for this t ----
        for (int z = tid; z < 651; z += 256) {
            int row, col;
            if (z < 264) { row = (z < 132) ? 0 : 130; col = z % 132; }
            else { int e = z - 264; int cc = e / 129; col = (cc == 0) ? 0 : (129 + cc); row = 1 + e % 129; }
            size_t o = ((size_t)t * 131 + row) * 132 + col;
            pmask[o] = 0;
            cnt[o] = 0;
        }
        // ---- w2 -> bf16 [ky][kx][112][32], chunk of 2800 per t ----
        int base = t * 2800;
        for (int k = 0; k < 11; ++k) {
            int idx = base + k * 256 + tid;
            if (idx < base + 2800) {
                int i  = idx & 31;
                int m  = (idx >> 5) % 112;
                int kk = idx / (112 * 32);
                int ky = kk / 5, kx = kk % 5;
                float v = 0.0f;
                if (m < 100 && i < 30) v = w2[((m * 30 + i) * 5 + ky) * 5 + kx];
                w2r[idx] = (bf16_t)v;
            }
        }
        return;
    }

    __shared__ __align__(16) unsigned Brows[24 * 2 * ROW_W]; // 26,112 B
    __shared__ __align__(16) unsigned Ms[4][2][256];         // 8 KB

    int py0 = bx * 4;
    int lane = tid & 63, wv = tid >> 6;
    int quad = lane >> 4, l15 = lane & 15;

    // ---- A fragments gathered inline from w1 (RNE converts; k = row*8+tap) ----
    bf16x8 afr[3][2];
    #pragma unroll
    for (int ks = 0; ks < 3; ++ks) {
        int i = ks * 4 + quad;                               // kernel row 0..11 (10,11 pad)
        #pragma unroll
        for (int mt = 0; mt < 2; ++mt) {
            int m = mt * 16 + l15;
            bool ok = (m < 30) & (i < 10);
            const float* wp = w1 + m * 50 + i * 5;           // in-bounds even when !ok
            bf16x8 a = {};
            #pragma unroll
            for (int j = 0; j < 5; ++j) a[j] = (bf16_t)(ok ? wp[j] : 0.0f);
            afr[ks][mt] = a;
        }
    }

    // zero edge words: per row phase0 {0,1,130..135}, phase1 {0,130..135}
    for (int z = tid; z < 24 * 15; z += 256) {
        int row = z / 15, e = z % 15;
        int w;
        if (e < 8) w = (e < 2) ? e : (128 + e);
        else { int e2 = e - 8; w = ROW_W + ((e2 == 0) ? 0 : (129 + e2)); }
        Brows[row * (2 * ROW_W) + w] = 0;
    }

    // stage 24 rows (2 ci x 12), coalesced, each float loaded once
    const float* inT = in + (size_t)t * 2 * 65536;
    #pragma unroll
    for (int k = 0; k < 6; ++k) {
        int seg = tid + k * 256;                             // 0..1535
        int row = seg >> 6, o = seg & 63;
        int ci = row / 12, s = row % 12;
        int iy = 2 * py0 - 3 + s;
        bool rv = (unsigned)iy < 256u;
        const float* rp = inT + ((size_t)ci * 256 + (rv ? iy : 0)) * 256 + 4 * o;
        f32x4 q = *(const f32x4*)rp;
        float v4 = (o < 63) ? rp[4] : 0.0f;
        if (!rv) { q = (f32x4){0.f, 0.f, 0.f, 0.f}; v4 = 0.0f; }
        unsigned base = row * (2 * ROW_W);
        int w = 2 * o + 2;
        *(uint2*)&Brows[base + w]         = make_uint2(pk2(q.x, q.y), pk2(q.z, q.w));
        *(uint2*)&Brows[base + ROW_W + w] = make_uint2(pk2(q.y, q.z), pk2(q.w, v4));
        if (o == 0) Brows[base + ROW_W + 1] = pk2(0.0f, q.x);
    }
    __syncthreads();

    // lane constants: phase + base word + per-ks row offset
    int phi = l15 & 1;
    int baseW = 1 + (l15 >> 1);
    int LC[3];
    #pragma unroll
    for (int ks = 0; ks < 3; ++ks) {
        int i = ks * 4 + quad;
        int cii = (i < 10) ? ((i < 5) ? 0 : 1) : 0;          // pad rows -> row 0 (A=0)
        int kyi = (i < 10) ? ((i < 5) ? i : i - 5) : 0;
        LC[ks] = (cii * 12 + kyi) * (2 * ROW_W) + phi * ROW_W + baseW;
    }

    int py = py0 + wv;                                       // this wave's pooled row
    #pragma unroll
    for (int rs01 = 0; rs01 < 2; ++rs01) {
        int r = 2 * py - 1 + rs01;
        unsigned vmask = ((unsigned)r < 256u) ? 0x3FFFFFFFu : 0u;
        int rbase = (2 * wv + rs01) * (2 * ROW_W);
        #pragma unroll 4
        for (int ptile = 0; ptile < 16; ++ptile) {
            f32x4 acc[2] = {};
            #pragma unroll
            for (int ks = 0; ks < 3; ++ks) {
                bf16x8 b = __builtin_bit_cast(bf16x8,
                    *(const bf16x8a4*)&Brows[LC[ks] + rbase + ptile * 8]);
                #pragma unroll
                for (int mt = 0; mt < 2; ++mt)
                    acc[mt] = __builtin_amdgcn_mfma_f32_16x16x32_bf16(afr[ks][mt], b, acc[mt], 0, 0, 0);
            }
            unsigned pm = 0;
            #pragma unroll
            for (int mt = 0; mt < 2; ++mt)
                #pragma unroll
                for (int rr = 0; rr < 4; ++rr)
                    if (acc[mt][rr] > 15.0f) pm |= 1u << (mt * 16 + quad * 4 + rr);
            pm |= __shfl_xor(pm, 16);
            pm |= __shfl_xor(pm, 32);
            pm &= vmask;
            if (quad == 0) Ms[wv][rs01][ptile * 16 + l15] = pm;
        }
    }

    // pool 2x2 -> pooled row py (per-wave, no barrier needed)
    if (py <= 128) {
        for (int px = lane; px < 129; px += 64) {
            int c0 = 2 * px - 1, c1 = 2 * px;
            unsigned m = 0;
            if (c0 >= 0)  m |= Ms[wv][0][c0] | Ms[wv][1][c0];
            if (c1 <= 255) m |= Ms[wv][0][c1] | Ms[wv][1][c1];
            size_t o = ((size_t)t * 131 + (py + 1)) * 132 + (px + 1);
            pmask[o] = m;
            cnt[o] = (unsigned char)__popc(m);
        }
    }
}

// ---------------- winmax: max 5x5-window spike count, plain per-block store ----------------
__global__ __launch_bounds__(256) void winmax_kernel(const unsigned char* __restrict__ cnt,
                                                     int* __restrict__ buckets) {
    int idx = blockIdx.x * 256 + threadIdx.x;                // 32*127*32 = 130,048 exact
    int t   = idx / (127 * 32);
    int r   = idx % (127 * 32);
    int oy  = r >> 5;
    int ox0 = (r & 31) * 4;                                  // 0..124
    const unsigned char* base = cnt + ((size_t)t * 131 + oy) * 132 + ox0;
    int w0 = 0, w1 = 0, w2 = 0, w3 = 0;
    #pragma unroll
    for (int dy = 0; dy < 5; ++dy) {
        u32x2u d = *(const u32x2u*)(base + dy * 132);
        int b0 = d.x & 255, b1 = (d.x >> 8) & 255, b2 = (d.x >> 16) & 255, b3 = d.x >> 24;
        int b4 = d.y & 255, b5 = (d.y >> 8) & 255, b6 = (d.y >> 16) & 255, b7 = d.y >> 24;
        int s14 = b1 + b2 + b3 + b4;
        w0 += b0 + s14;
        w1 += s14 + b5;
        int s36 = b3 + b4 + b5 + b6;
        w2 += b2 + s36;
        w3 += s36 + b7;
    }
    int m = w0;
    if (ox0 + 1 <= 126) m = max(m, w1);
    if (ox0 + 2 <= 126) m = max(m, w2);
    if (ox0 + 3 <= 126) m = max(m, w3);
    #pragma unroll
    for (int off = 32; off; off >>= 1) m = max(m, __shfl_xor(m, off));
    __shared__ int sm[4];
    if ((threadIdx.x & 63) == 0) sm[threadIdx.x >> 6] = m;
    __syncthreads();
    if (threadIdx.x == 0)
        buckets[blockIdx.x] = max(max(sm[0], sm[1]), max(sm[2], sm[3]));
}

// ---------------- decide: block c -> S from buckets, min/max of w2[c], out + unproven ----------------
__global__ __launch_bounds__(256) void decide_kernel(const float* __restrict__ w2,
                                                     const int* __restrict__ buckets,
                                                     float* __restrict__ out,
                                                     int* __restrict__ unproven) {
    int c = blockIdx.x;                                      // 0..99
    int tid = threadIdx.x;
    int m = 0;
    for (int i = tid; i < N_WM_BLK; i += 256) m = max(m, buckets[i]);
    float lo = 1e30f, hi = -1e30f;
    for (int i = tid; i < 750; i += 256) {
        float v = w2[c * 750 + i];
        lo = fminf(lo, v); hi = fmaxf(hi, v);
    }
    #pragma unroll
    for (int off = 32; off; off >>= 1) {
        m  = max(m, __shfl_xor(m, off));
        lo = fminf(lo, __shfl_xor(lo, off));
        hi = fmaxf(hi, __shfl_xor(hi, off));
    }
    __shared__ int smv[4];
    __shared__ float smn[4], smx[4];
    if ((tid & 63) == 0) { smv[tid >> 6] = m; smn[tid >> 6] = lo; smx[tid >> 6] = hi; }
    __syncthreads();
    if (tid == 0) {
        int Si = max(max(smv[0], smv[1]), max(smv[2], smv[3]));
        float l = fminf(fminf(smn[0], smn[1]), fminf(smn[2], smn[3]));
        float h = fmaxf(fmaxf(smx[0], smx[1]), fmaxf(smx[2], smx[3]));
        float S = (float)Si;
        bool fire = (l >= 0.0f) && (S * l > 10.5f);          // margin >> fp rounding
        bool zero = (h <= 0.0f) || (S * h < 9.5f);
        out[c] = fire ? 1.0f : 0.0f;
        unproven[c] = (!fire && !zero) ? 1 : 0;
    }
}

// ---------------- fallback: exact conv2 (bf16 MFMA) from pmask, runs only if unproven ----------------
__global__ __launch_bounds__(256, 2) void conv2_any_kernel(const unsigned* __restrict__ pmask,
                                                           const bf16_t* __restrict__ w2r,
                                                           float* __restrict__ out,
                                                           const int* __restrict__ unproven) {
    int tid = threadIdx.x;
    int lane = tid & 63, wvv = tid >> 6;

    // early exit: all channels proven by bounds?
    {
        int v = (tid < 100) ? unproven[tid] : 0;
        unsigned long long any = __ballot(v != 0);
        __shared__ int s[4];
        s[wvv] = (any != 0ull) ? 1 : 0;
        __syncthreads();
        if ((s[0] | s[1] | s[2] | s[3]) == 0) return;
        __syncthreads();
    }

    __shared__ __align__(16) bf16_t Bt[5 * 132 * 32];
    __shared__ __align__(16) bf16_t At[5 * 112 * 32];

    int oy = blockIdx.x % 127, tg = blockIdx.x / 127;
    int quad = lane >> 4, l15 = lane & 15;
    int n0 = wvv * 32 + l15;

    for (int it = 0; it < 8; ++it) {
        int t = tg * 8 + it;
        __syncthreads();

        for (int p = tid; p < 5 * 132; p += 256) {
            int row = p / 132, x = p % 132;
            unsigned m = pmask[((size_t)t * 131 + oy + row) * 132 + x];
            uint4* dst = (uint4*)(Bt + (size_t)p * 32);
            #pragma unroll
            for (int g = 0; g < 4; ++g) {
                unsigned ws[4];
                #pragma unroll
                for (int q = 0; q < 4; ++q) {
                    int i2 = g * 4 + q;
                    unsigned lo = ((m >> (2 * i2)) & 1u) ? 0x3F80u : 0u;
                    unsigned hi = ((m >> (2 * i2 + 1)) & 1u) ? 0x3F80u : 0u;
                    ws[q] = lo | (hi << 16);
                }
                dst[g] = make_uint4(ws[0], ws[1], ws[2], ws[3]);
            }
        }

        f32x4 acc[7][2] = {};
        for (int ky = 0; ky < 5; ++ky) {
            __syncthreads();
            const bf16_t* asrc = w2r + (size_t)ky * (5 * 112 * 32);
            for (int off = tid * 8; off < 5 * 112 * 32; off += 256 * 8)
                *(uint4*)(At + off) = *(const uint4*)(asrc + off);
            __syncthreads();

            #pragma unroll
            for (int kx = 0; kx < 5; ++kx) {
                bf16x8 a[7], b[2];
                #pragma unroll
                for (int mt = 0; mt < 7; ++mt)
                    a[mt] = *(const bf16x8*)(At + ((kx * 112 + mt * 16 + l15) * 32 + quad * 8));
                #pragma unroll
                for (int j = 0; j < 2; ++j) {
                    int x = n0 + j * 16 + kx;
                    b[j] = *(const bf16x8*)(Bt + ((ky * 132 + x) * 32 + quad * 8));
                }
                #pragma unroll
                for (int mt = 0; mt < 7; ++mt)
                    #pragma unroll
                    for (int j = 0; j < 2; ++j)
                        acc[mt][j] = __builtin_amdgcn_mfma_f32_16x16x32_bf16(a[mt], b[j], acc[mt][j], 0, 0, 0);
            }
        }

        int ox0 = n0, ox1 = n0 + 16;
        #pragma unroll
        for (int mt = 0; mt < 7; ++mt) {
            #pragma unroll
            for (int r = 0; r < 4; ++r) {
                int c = mt * 16 + quad * 4 + r;
                bool f0 = (acc[mt][0][r] > 10.0f) && (ox0 < 127);
                bool f1 = (acc[mt][1][r] > 10.0f) && (ox1 < 127);
                if (c < 100 && (f0 || f1)) out[c] = 1.0f;
            }
        }
    }
}

// ---------------- launch: 4 dispatches, no memset ----------------
extern "C" void kernel_launch(void* const* d_in, const int* in_sizes, int n_in,
                              void* d_out, int out_size, void* d_ws, size_t ws_size,
                              hipStream_t stream) {
    const float* in = (const float*)d_in[0];
    const float* w1 = (const float*)d_in[1];
    const float* w2 = (const float*)d_in[2];
    float* out = (float*)d_out;

    char* ws = (char*)d_ws;
    unsigned*      pmask = (unsigned*)(ws + OFF_PMASK);
    unsigned char* cnt   = (unsigned char*)(ws + OFF_CNT);
    int*           buck  = (int*)(ws + OFF_BUCK);
    int*           unpr  = (int*)(ws + OFF_UNPR);
    bf16_t*        w2r   = (bf16_t*)(ws + OFF_W2R);

    conv1_mfma_kernel<<<dim3(34, 32), 256, 0, stream>>>(in, w1, w2, pmask, cnt, w2r);
    winmax_kernel<<<N_WM_BLK, 256, 0, stream>>>(cnt, buck);
    decide_kernel<<<100, 256, 0, stream>>>(w2, buck, out, unpr);
    conv2_any_kernel<<<508, 256, 0, stream>>>(pmask, w2r, out, unpr);
}

// Round 8
// 82.961 us; speedup vs baseline: 4.2849x; 1.1923x over previous
//
#include <hip/hip_runtime.h>
#include <hip/hip_bf16.h>

typedef __bf16 bf16_t;
typedef bf16_t bf16x8 __attribute__((ext_vector_type(8)));
typedef bf16_t bf16x8a4 __attribute__((ext_vector_type(8), aligned(4)));
typedef float f32x4 __attribute__((ext_vector_type(4)));

// ---------------- constants ----------------
// input: [32, 2, 256, 256] fp32 binary ; w1: [30,2,5,5] fp32 ; w2: [100,30,5,5] fp32
// pooled spikes as 30-bit masks: pmask [32][131][132] uint (ring zeroed by aux blocks,
// only in the fallback path)
#define PMASK_ELEMS ((size_t)32 * 131 * 132)                 // 553,344
#define PMASK_BYTES (PMASK_ELEMS * 4)
#define W2R_ELEMS   (5 * 5 * 112 * 32)                       // 89,600

// ws layout (no zero-init required anywhere)
#define OFF_PMASK ((size_t)0)
#define OFF_W2R   ((OFF_PMASK + PMASK_BYTES + 15) & ~(size_t)15)
#define OFF_MN    (OFF_W2R + W2R_ELEMS * 2)
#define OFF_SSLOT (OFF_MN + 400)
#define OFF_FLAG  (OFF_SSLOT + 16)

// pack two binary floats (0.0/1.0) into one uint of 2 bf16 (exact: bf16 = fp32>>16)
__device__ __forceinline__ unsigned pk2(float a, float b) {
    return (__builtin_bit_cast(unsigned, a) >> 16) |
           (__builtin_bit_cast(unsigned, b) & 0xFFFF0000u);
}

// ---------------- probe: per-channel w2 min (blocks 0..99) + 4 exact windows (100..103) ----------------
// Window w: t = 8w, pooled rows/cols 61..65 -> conv pixels 121..130 (all interior).
// Computes exact fp32 conv1 + fire(15) + 2x2 pool + 5x5 window spike count -> sslot[w].
__global__ __launch_bounds__(256) void probe_kernel(const float* __restrict__ in,
                                                    const float* __restrict__ w1,
                                                    const float* __restrict__ w2,
                                                    float* __restrict__ mn,
                                                    int* __restrict__ sslot) {
    int bx = blockIdx.x, tid = threadIdx.x;
    if (bx < 100) {
        float lo = 1e30f;
        for (int i = tid; i < 750; i += 256) lo = fminf(lo, w2[bx * 750 + i]);
        #pragma unroll
        for (int off = 32; off; off >>= 1) lo = fminf(lo, __shfl_xor(lo, off));
        __shared__ float sm[4];
        if ((tid & 63) == 0) sm[tid >> 6] = lo;
        __syncthreads();
        if (tid == 0) mn[bx] = fminf(fminf(sm[0], sm[1]), fminf(sm[2], sm[3]));
        return;
    }

    int w = bx - 100;                                        // 0..3
    int t = w * 8;
    __shared__ float patch[2][14][14];                       // input rows/cols 119..132
    __shared__ unsigned fire[100];                           // conv-pixel 30-bit fire masks

    for (int i = tid; i < 392; i += 256) {
        int ci = i / 196, r = (i % 196) / 14, cl = i % 14;
        patch[ci][r][cl] = in[(((size_t)t * 2 + ci) * 256 + (119 + r)) * 256 + (119 + cl)];
    }
    for (int i = tid; i < 100; i += 256) fire[i] = 0;
    __syncthreads();

    // task = c*100 + p : conv pixel p (10x10), channel c
    for (int task = tid; task < 3000; task += 256) {
        int c = task / 100, p = task % 100;
        int ly = p / 10, lx = p % 10;
        const float* wc = w1 + c * 50;
        float a0 = 0.f, a1 = 0.f;
        #pragma unroll
        for (int ci = 0; ci < 2; ++ci)
            #pragma unroll
            for (int ky = 0; ky < 5; ++ky) {
                const float* pr = &patch[ci][ly + ky][lx];
                const float* wr = wc + ci * 25 + ky * 5;
                a0 = fmaf(wr[0], pr[0], a0);
                a1 = fmaf(wr[1], pr[1], a1);
                a0 = fmaf(wr[2], pr[2], a0);
                a1 = fmaf(wr[3], pr[3], a1);
                a0 = fmaf(wr[4], pr[4], a0);
            }
        if (a0 + a1 > 15.0f) atomicOr(&fire[p], 1u << c);
    }
    __syncthreads();

    if (tid < 64) {
        int s = 0;
        if (tid < 25) {
            int qy = tid / 5, qx = tid % 5;
            unsigned m = fire[(2 * qy) * 10 + 2 * qx]     | fire[(2 * qy) * 10 + 2 * qx + 1] |
                         fire[(2 * qy + 1) * 10 + 2 * qx] | fire[(2 * qy + 1) * 10 + 2 * qx + 1];
            s = __popc(m);
        }
        #pragma unroll
        for (int off = 32; off; off >>= 1) s += __shfl_xor(s, off);
        if (tid == 0) sslot[w] = s;
    }
}

// ---------------- decide: out[c] from lower-bound proof; need_full flag ----------------
__global__ __launch_bounds__(128) void decide_kernel(const float* __restrict__ mn,
                                                     const int* __restrict__ sslot,
                                                     float* __restrict__ out,
                                                     int* __restrict__ flag) {
    int tid = threadIdx.x;
    int S = max(max(sslot[0], sslot[1]), max(sslot[2], sslot[3]));
    bool unproven = false;
    if (tid < 100) {
        float m = mn[tid];
        // true S >= S_probe; -2 absorbs any threshold-rounding drift in the probe
        bool fire = (m >= 0.0f) && ((float)(S - 2) * m > 10.5f);
        out[tid] = fire ? 1.0f : 0.0f;
        unproven = !fire;
    }
    unsigned long long b = __ballot(unproven);
    __shared__ int sany[2];
    if ((tid & 63) == 0) sany[tid >> 6] = (b != 0ull) ? 1 : 0;
    __syncthreads();
    if (tid == 0) flag[0] = sany[0] | sany[1];
}

// ---------------- fallback conv1 via MFMA (flag-gated); aux blocks: ring-zero + w2 repack ----------------
#define ROW_W 136                                            // words per phase (pad incl.)
__global__ __launch_bounds__(256, 4) void conv1_mfma_kernel(const float* __restrict__ in,
                                                            const float* __restrict__ w1,
                                                            const float* __restrict__ w2,
                                                            unsigned* __restrict__ pmask,
                                                            bf16_t* __restrict__ w2r,
                                                            const int* __restrict__ flag) {
    if (flag[0] == 0) return;                                // proven by probe: exit fast

    int bx = blockIdx.x;
    int t  = blockIdx.y;
    int tid = threadIdx.x;

    if (bx == 33) {
        // zero pmask ring for this t
        for (int z = tid; z < 651; z += 256) {
            int row, col;
            if (z < 264) { row = (z < 132) ? 0 : 130; col = z % 132; }
            else { int e = z - 264; int cc = e / 129; col = (cc == 0) ? 0 : (129 + cc); row = 1 + e % 129; }
            pmask[((size_t)t * 131 + row) * 132 + col] = 0;
        }
        // w2 -> bf16 [ky][kx][112][32], chunk of 2800 per t
        int base = t * 2800;
        for (int k = 0; k < 11; ++k) {
            int idx = base + k * 256 + tid;
            if (idx < base + 2800) {
                int i  = idx & 31;
                int m  = (idx >> 5) % 112;
                int kk = idx / (112 * 32);
                int ky = kk / 5, kx = kk % 5;
                float v = 0.0f;
                if (m < 100 && i < 30) v = w2[((m * 30 + i) * 5 + ky) * 5 + kx];
                w2r[idx] = (bf16_t)v;
            }
        }
        return;
    }

    __shared__ __align__(16) unsigned Brows[24 * 2 * ROW_W];
    __shared__ __align__(16) unsigned Ms[4][2][256];

    int py0 = bx * 4;
    int lane = tid & 63, wv = tid >> 6;
    int quad = lane >> 4, l15 = lane & 15;

    // A fragments gathered inline from w1 (k = row*8 + tap)
    bf16x8 afr[3][2];
    #pragma unroll
    for (int ks = 0; ks < 3; ++ks) {
        int i = ks * 4 + quad;
        #pragma unroll
        for (int mt = 0; mt < 2; ++mt) {
            int m = mt * 16 + l15;
            bool ok = (m < 30) & (i < 10);
            const float* wp = w1 + m * 50 + i * 5;
            bf16x8 a = {};
            #pragma unroll
            for (int j = 0; j < 5; ++j) a[j] = (bf16_t)(ok ? wp[j] : 0.0f);
            afr[ks][mt] = a;
        }
    }

    for (int z = tid; z < 24 * 15; z += 256) {
        int row = z / 15, e = z % 15;
        int w;
        if (e < 8) w = (e < 2) ? e : (128 + e);
        else { int e2 = e - 8; w = ROW_W + ((e2 == 0) ? 0 : (129 + e2)); }
        Brows[row * (2 * ROW_W) + w] = 0;
    }

    const float* inT = in + (size_t)t * 2 * 65536;
    #pragma unroll
    for (int k = 0; k < 6; ++k) {
        int seg = tid + k * 256;
        int row = seg >> 6, o = seg & 63;
        int ci = row / 12, s = row % 12;
        int iy = 2 * py0 - 3 + s;
        bool rv = (unsigned)iy < 256u;
        const float* rp = inT + ((size_t)ci * 256 + (rv ? iy : 0)) * 256 + 4 * o;
        f32x4 q = *(const f32x4*)rp;
        float v4 = (o < 63) ? rp[4] : 0.0f;
        if (!rv) { q = (f32x4){0.f, 0.f, 0.f, 0.f}; v4 = 0.0f; }
        unsigned base = row * (2 * ROW_W);
        int w = 2 * o + 2;
        *(uint2*)&Brows[base + w]         = make_uint2(pk2(q.x, q.y), pk2(q.z, q.w));
        *(uint2*)&Brows[base + ROW_W + w] = make_uint2(pk2(q.y, q.z), pk2(q.w, v4));
        if (o == 0) Brows[base + ROW_W + 1] = pk2(0.0f, q.x);
    }
    __syncthreads();

    int phi = l15 & 1;
    int baseW = 1 + (l15 >> 1);
    int LC[3];
    #pragma unroll
    for (int ks = 0; ks < 3; ++ks) {
        int i = ks * 4 + quad;
        int cii = (i < 10) ? ((i < 5) ? 0 : 1) : 0;
        int kyi = (i < 10) ? ((i < 5) ? i : i - 5) : 0;
        LC[ks] = (cii * 12 + kyi) * (2 * ROW_W) + phi * ROW_W + baseW;
    }

    int py = py0 + wv;
    #pragma unroll
    for (int rs01 = 0; rs01 < 2; ++rs01) {
        int r = 2 * py - 1 + rs01;
        unsigned vmask = ((unsigned)r < 256u) ? 0x3FFFFFFFu : 0u;
        int rbase = (2 * wv + rs01) * (2 * ROW_W);
        #pragma unroll 4
        for (int ptile = 0; ptile < 16; ++ptile) {
            f32x4 acc[2] = {};
            #pragma unroll
            for (int ks = 0; ks < 3; ++ks) {
                bf16x8 b = __builtin_bit_cast(bf16x8,
                    *(const bf16x8a4*)&Brows[LC[ks] + rbase + ptile * 8]);
                #pragma unroll
                for (int mt = 0; mt < 2; ++mt)
                    acc[mt] = __builtin_amdgcn_mfma_f32_16x16x32_bf16(afr[ks][mt], b, acc[mt], 0, 0, 0);
            }
            unsigned pm = 0;
            #pragma unroll
            for (int mt = 0; mt < 2; ++mt)
                #pragma unroll
                for (int rr = 0; rr < 4; ++rr)
                    if (acc[mt][rr] > 15.0f) pm |= 1u << (mt * 16 + quad * 4 + rr);
            pm |= __shfl_xor(pm, 16);
            pm |= __shfl_xor(pm, 32);
            pm &= vmask;
            if (quad == 0) Ms[wv][rs01][ptile * 16 + l15] = pm;
        }
    }

    if (py <= 128) {
        for (int px = lane; px < 129; px += 64) {
            int c0 = 2 * px - 1, c1 = 2 * px;
            unsigned m = 0;
            if (c0 >= 0)  m |= Ms[wv][0][c0] | Ms[wv][1][c0];
            if (c1 <= 255) m |= Ms[wv][0][c1] | Ms[wv][1][c1];
            pmask[((size_t)t * 131 + (py + 1)) * 132 + (px + 1)] = m;
        }
    }
}

// ---------------- fallback conv2: exact bf16 MFMA from pmask (flag-gated) ----------------
__global__ __launch_bounds__(256, 2) void conv2_any_kernel(const unsigned* __restrict__ pmask,
                                                           const bf16_t* __restrict__ w2r,
                                                           float* __restrict__ out,
                                                           const int* __restrict__ flag) {
    if (flag[0] == 0) return;

    __shared__ __align__(16) bf16_t Bt[5 * 132 * 32];
    __shared__ __align__(16) bf16_t At[5 * 112 * 32];

    int tid = threadIdx.x;
    int lane = tid & 63, wvv = tid >> 6;
    int oy = blockIdx.x % 127, tg = blockIdx.x / 127;
    int quad = lane >> 4, l15 = lane & 15;
    int n0 = wvv * 32 + l15;

    for (int it = 0; it < 8; ++it) {
        int t = tg * 8 + it;
        __syncthreads();

        for (int p = tid; p < 5 * 132; p += 256) {
            int row = p / 132, x = p % 132;
            unsigned m = pmask[((size_t)t * 131 + oy + row) * 132 + x];
            uint4* dst = (uint4*)(Bt + (size_t)p * 32);
            #pragma unroll
            for (int g = 0; g < 4; ++g) {
                unsigned ws[4];
                #pragma unroll
                for (int q = 0; q < 4; ++q) {
                    int i2 = g * 4 + q;
                    unsigned lo = ((m >> (2 * i2)) & 1u) ? 0x3F80u : 0u;
                    unsigned hi = ((m >> (2 * i2 + 1)) & 1u) ? 0x3F80u : 0u;
                    ws[q] = lo | (hi << 16);
                }
                dst[g] = make_uint4(ws[0], ws[1], ws[2], ws[3]);
            }
        }

        f32x4 acc[7][2] = {};
        for (int ky = 0; ky < 5; ++ky) {
            __syncthreads();
            const bf16_t* asrc = w2r + (size_t)ky * (5 * 112 * 32);
            for (int off = tid * 8; off < 5 * 112 * 32; off += 256 * 8)
                *(uint4*)(At + off) = *(const uint4*)(asrc + off);
            __syncthreads();

            #pragma unroll
            for (int kx = 0; kx < 5; ++kx) {
                bf16x8 a[7], b[2];
                #pragma unroll
                for (int mt = 0; mt < 7; ++mt)
                    a[mt] = *(const bf16x8*)(At + ((kx * 112 + mt * 16 + l15) * 32 + quad * 8));
                #pragma unroll
                for (int j = 0; j < 2; ++j) {
                    int x = n0 + j * 16 + kx;
                    b[j] = *(const bf16x8*)(Bt + ((ky * 132 + x) * 32 + quad * 8));
                }
                #pragma unroll
                for (int mt = 0; mt < 7; ++mt)
                    #pragma unroll
                    for (int j = 0; j < 2; ++j)
                        acc[mt][j] = __builtin_amdgcn_mfma_f32_16x16x32_bf16(a[mt], b[j], acc[mt][j], 0, 0, 0);
            }
        }

        int ox0 = n0, ox1 = n0 + 16;
        #pragma unroll
        for (int mt = 0; mt < 7; ++mt) {
            #pragma unroll
            for (int r = 0; r < 4; ++r) {
                int c = mt * 16 + quad * 4 + r;
                bool f0 = (acc[mt][0][r] > 10.0f) && (ox0 < 127);
                bool f1 = (acc[mt][1][r] > 10.0f) && (ox1 < 127);
                if (c < 100 && (f0 || f1)) out[c] = 1.0f;
            }
        }
    }
}

// ---------------- launch ----------------
extern "C" void kernel_launch(void* const* d_in, const int* in_sizes, int n_in,
                              void* d_out, int out_size, void* d_ws, size_t ws_size,
                              hipStream_t stream) {
    const float* in = (const float*)d_in[0];
    const float* w1 = (const float*)d_in[1];
    const float* w2 = (const float*)d_in[2];
    float* out = (float*)d_out;

    char* ws = (char*)d_ws;
    unsigned* pmask = (unsigned*)(ws + OFF_PMASK);
    bf16_t*   w2r   = (bf16_t*)(ws + OFF_W2R);
    float*    mn    = (float*)(ws + OFF_MN);
    int*      sslot = (int*)(ws + OFF_SSLOT);
    int*      flag  = (int*)(ws + OFF_FLAG);

    probe_kernel<<<104, 256, 0, stream>>>(in, w1, w2, mn, sslot);
    decide_kernel<<<1, 128, 0, stream>>>(mn, sslot, out, flag);
    conv1_mfma_kernel<<<dim3(34, 32), 256, 0, stream>>>(in, w1, w2, pmask, w2r, flag);
    conv2_any_kernel<<<508, 256, 0, stream>>>(pmask, w2r, out, flag);
}